// Round 1
// baseline (508.591 us; speedup 1.0000x reference)
//
#include <hip/hip_runtime.h>
#include <hip/hip_bf16.h>

// Problem constants
#define BB   2
#define NN   50000
#define BN   100000     // B*N
#define NE   500000
#define NSB  196        // scan blocks = ceil(NN/256)

using u16 = unsigned short;
using u32 = unsigned int;
typedef __attribute__((ext_vector_type(8))) short short8;      // 8 x bf16/f16 bits
typedef __attribute__((ext_vector_type(8))) _Float16 half8;    // 8 x f16 (4 VGPRs)
typedef __attribute__((ext_vector_type(4))) float f32x4;       // MFMA accumulator

__device__ __forceinline__ u16 f2bf(float f) {   // RNE f32 -> bf16 (finite inputs)
    union { float f; u32 u; } w; w.f = f;
    return (u16)((w.u + 0x7fffu + ((w.u >> 16) & 1u)) >> 16);
}
__device__ __forceinline__ u16 f2h(float f) {    // RNE f32 -> f16
    _Float16 h = (_Float16)f; u16 u; __builtin_memcpy(&u, &h, 2); return u;
}

#if defined(__has_builtin)
#if __has_builtin(__builtin_amdgcn_cvt_pk_bf16_f32)
#define HAVE_CVTPK 1
#endif
#if __has_builtin(__builtin_amdgcn_cvt_pkrtz)
#define HAVE_PKRTZ 1
#endif
#endif

__device__ __forceinline__ u32 pack_bf(float lo, float hi) {
#ifdef HAVE_CVTPK
    auto r = __builtin_amdgcn_cvt_pk_bf16_f32(lo, hi);
    u32 out; __builtin_memcpy(&out, &r, sizeof(out));
    return out;
#else
    return ((u32)f2bf(hi) << 16) | (u32)f2bf(lo);
#endif
}

__device__ __forceinline__ u32 pack_h2(float lo, float hi) {
#ifdef HAVE_PKRTZ
    auto r = __builtin_amdgcn_cvt_pkrtz(lo, hi);
    u32 out; __builtin_memcpy(&out, &r, sizeof(out));
    return out;
#else
    return ((u32)f2h(hi) << 16) | (u32)f2h(lo);
#endif
}

__device__ __forceinline__ u32 pk_add_h2(u32 a, u32 b) {
    u32 d; asm("v_pk_add_f16 %0, %1, %2" : "=v"(d) : "v"(a), "v"(b)); return d;
}
__device__ __forceinline__ u32 pk_relu_h2(u32 a) {
    u32 d, z = 0u;
    asm("v_pk_max_f16 %0, %1, %2" : "=v"(d) : "v"(a), "v"(z)); return d;
}
__device__ __forceinline__ half8 as_h8(short8 s) {
    half8 h; __builtin_memcpy(&h, &s, 16); return h;
}

// ---------------------------------------------------------------------------
// CSR build: node -> contiguous slots [off[n], off[n+1]) ; eidx[slot] = edge id
// (each edge occupies one slot under u and one under v).
// ---------------------------------------------------------------------------
__global__ __launch_bounds__(256) void csr_zero(int* __restrict__ cursor) {
    int i = blockIdx.x * 256 + threadIdx.x;
    if (i < NN) cursor[i] = 0;
}

__global__ __launch_bounds__(256) void csr_hist(const int* __restrict__ edges,
                                                int* __restrict__ cursor) {
    int e = blockIdx.x * 256 + threadIdx.x;
    if (e < NE) {
        atomicAdd(&cursor[edges[2*e]], 1);
        atomicAdd(&cursor[edges[2*e+1]], 1);
    }
}

__global__ __launch_bounds__(256) void scan_pass1(const int* __restrict__ cursor,
                                                  int* __restrict__ bsum) {
    __shared__ int s[256];
    const int t = threadIdx.x;
    int i = blockIdx.x * 256 + t;
    s[t] = (i < NN) ? cursor[i] : 0;
    __syncthreads();
    for (int d = 128; d > 0; d >>= 1) {
        if (t < d) s[t] += s[t + d];
        __syncthreads();
    }
    if (t == 0) bsum[blockIdx.x] = s[0];
}

__global__ __launch_bounds__(256) void scan_pass2(const int* __restrict__ bsum,
                                                  int* __restrict__ boff) {
    __shared__ int s[256];
    const int t = threadIdx.x;
    s[t] = (t < NSB) ? bsum[t] : 0;
    __syncthreads();
    for (int d = 1; d < 256; d <<= 1) {
        int v = (t >= d) ? s[t - d] : 0;
        __syncthreads();
        s[t] += v;
        __syncthreads();
    }
    if (t <= NSB) boff[t] = (t == 0) ? 0 : s[t - 1];
}

__global__ __launch_bounds__(256) void scan_pass3(int* __restrict__ cursor,
                                                  const int* __restrict__ boff,
                                                  int* __restrict__ off) {
    __shared__ int s[256];
    const int t = threadIdx.x;
    int i = blockIdx.x * 256 + t;
    int v = (i < NN) ? cursor[i] : 0;
    s[t] = v;
    __syncthreads();
    for (int d = 1; d < 256; d <<= 1) {
        int p = (t >= d) ? s[t - d] : 0;
        __syncthreads();
        s[t] += p;
        __syncthreads();
    }
    int excl = boff[blockIdx.x] + s[t] - v;
    if (i < NN) { off[i] = excl; cursor[i] = excl; }
    if (i == NN - 1) off[NN] = excl + v;
}

__global__ __launch_bounds__(256) void csr_fill(const int* __restrict__ edges,
                                                int* __restrict__ cursor,
                                                int* __restrict__ eidx) {
    int e = blockIdx.x * 256 + threadIdx.x;
    if (e < NE) {
        int s0 = atomicAdd(&cursor[edges[2*e]], 1);
        eidx[s0] = e;
        int s1 = atomicAdd(&cursor[edges[2*e+1]], 1);
        eidx[s1] = e;
    }
}

// ---------------------------------------------------------------------------
// Unified weight prep: blocks 0..191 swizzle w1 (A-frag layout, bf16),
// 192..319 compute fused W2' = W2@dw into A-frag (ew2 region in F16 for the
// f16 edge GEMM2; nw2 region stays bf16), block 320 fuses biases.
// Regions (u16): w1e @0 ([16][4][64][8]), w1n @32768 ([16][2][64][8]),
//                w2e' @49152 ([4][8][64][8], f16), w2n' @65536 ([4][8][64][8]).
// ---------------------------------------------------------------------------
__global__ __launch_bounds__(256) void weight_prep(
    const float* __restrict__ ew1, const float* __restrict__ nw1,
    const float* __restrict__ ew2, const float* __restrict__ nw2,
    const float* __restrict__ dw,  const float* __restrict__ db,
    const float* __restrict__ eb2, const float* __restrict__ nb2,
    u16* __restrict__ frag, float* __restrict__ bias2)
{
    int blk = blockIdx.x, t = threadIdx.x;
    if (blk < 192) {
        int idx = blk * 256 + t;                 // 0..49151
        const float* src; int KB, local;
        if (idx < 32768) { local = idx;         src = ew1; KB = 4; }
        else             { local = idx - 32768; src = nw1; KB = 2; }
        int j = local & 7, l = (local >> 3) & 63, rest = local >> 9;
        int kblk = rest % KB, ntile = rest / KB;
        int n = ntile * 16 + (l & 15);
        int k = kblk * 32 + ((l >> 4) << 3) + j;
        frag[idx] = f2bf(src[k * 256 + n]);
    } else if (blk < 320) {
        int idx = (blk - 192) * 256 + t;         // 0..32767
        bool is_e = (idx < 16384);
        const float* src = is_e ? ew2 : nw2;
        int local = idx & 16383;
        int j = local & 7, l = (local >> 3) & 63, rest = local >> 9;
        int kblk = rest & 7, ntile = rest >> 3;
        int n = ntile * 16 + (l & 15);
        int k = kblk * 32 + ((l >> 4) << 3) + j;
        float s = 0.f;
        for (int jj = 0; jj < 128; ++jj) s = fmaf(src[k * 128 + jj], dw[jj * 64 + n], s);
        frag[49152 + idx] = is_e ? f2h(s) : f2bf(s);
    } else if (t < 128) {
        int d = t & 63;
        const float* bsrc = (t >= 64) ? nb2 : eb2;
        float s = 0.f;
        #pragma unroll 4
        for (int j = 0; j < 128; ++j) s = fmaf(bsrc[j], dw[j * 64 + d], s);
        if (t >= 64) bias2[64 + d] = s + db[d];
        else         bias2[d] = s;
    }
}

// ---------------------------------------------------------------------------
// Node MLP (dw-fused) + x f32->bf16 conversion. (unchanged)
// ---------------------------------------------------------------------------
__global__ __launch_bounds__(256) void node_mlp_kernel(
    const float* __restrict__ x, const float* __restrict__ nb1,
    const float* __restrict__ bias2, const u16* __restrict__ frag,
    u16* __restrict__ xbf, float* __restrict__ out)
{
    __shared__ u16 xs[64 * 64];     // 8 KB, 8 chunks/row, swizzle mask 7
    __shared__ u16 hid[64 * 256];   // 32 KB, 32 chunks/row, swizzle mask 15
    const int t = threadIdx.x;
    const int wave = t >> 6, l = t & 63, lane15 = l & 15, quad = l >> 4;
    const int r0 = blockIdx.x * 64;
    const int valid = min(64, BN - r0);

    #pragma unroll
    for (int it = 0; it < 4; ++it) {
        int i = t + it * 256;          // 0..1023
        int m = i >> 4, c4 = i & 15;   // row, float4-col (8B half-chunk)
        int row = min(r0 + m, BN - 1);
        float4 g = ((const float4*)x)[(size_t)row * 16 + c4];
        uint2 q = make_uint2(pack_bf(g.x, g.y), pack_bf(g.z, g.w));
        int chunk = c4 >> 1;
        *(uint2*)(xs + m * 64 + ((chunk ^ (m & 7)) << 3) + (c4 & 1) * 4) = q;
        *(uint2*)(xbf + (size_t)row * 64 + c4 * 4) = q;
    }
    __syncthreads();

    {   // GEMM1^T, K=64
        f32x4 acc[4][4];
        #pragma unroll
        for (int i = 0; i < 4; ++i)
            #pragma unroll
            for (int mt = 0; mt < 4; ++mt) acc[i][mt] = f32x4{0.f,0.f,0.f,0.f};
        const u16* w1 = frag + 32768;    // [16][2][64][8]
        #pragma unroll
        for (int kblk = 0; kblk < 2; ++kblk) {
            short8 bf[4], af[4];
            int chunk = kblk * 4 + quad;
            #pragma unroll
            for (int mt = 0; mt < 4; ++mt) {
                int row = mt*16 + lane15;
                bf[mt] = *(const short8*)(xs + row * 64 + ((chunk ^ (row & 7)) << 3));
            }
            #pragma unroll
            for (int i = 0; i < 4; ++i)
                af[i] = *(const short8*)(w1 + (((wave*4 + i)*2 + kblk)*64 + l) * 8);
            #pragma unroll
            for (int i = 0; i < 4; ++i)
                #pragma unroll
                for (int mt = 0; mt < 4; ++mt)
                    acc[i][mt] = __builtin_amdgcn_mfma_f32_16x16x32_bf16(af[i], bf[mt], acc[i][mt], 0, 0, 0);
        }
        #pragma unroll
        for (int i = 0; i < 4; ++i) {
            int n0 = (wave*4 + i)*16 + quad*4;
            int chunk = (wave*4 + i)*2 + (quad >> 1);
            float4 bv = *(const float4*)(nb1 + n0);
            #pragma unroll
            for (int mt = 0; mt < 4; ++mt) {
                int row = mt*16 + lane15;
                uint2 q = make_uint2(
                    pack_bf(fmaxf(acc[i][mt][0] + bv.x, 0.f), fmaxf(acc[i][mt][1] + bv.y, 0.f)),
                    pack_bf(fmaxf(acc[i][mt][2] + bv.z, 0.f), fmaxf(acc[i][mt][3] + bv.w, 0.f)));
                *(uint2*)(hid + row * 256 + ((chunk ^ (row & 15)) << 3) + (quad & 1) * 4) = q;
            }
        }
    }
    __syncthreads();

    {   // fused GEMM2^T: N=64, K=256 -> f32 out
        f32x4 acc[4];
        #pragma unroll
        for (int mt = 0; mt < 4; ++mt) acc[mt] = f32x4{0.f,0.f,0.f,0.f};
        const u16* w2 = frag + 65536;    // [4][8][64][8], ntile = wave
        #pragma unroll
        for (int kblk = 0; kblk < 8; ++kblk) {
            short8 bf[4], af;
            int chunk = kblk * 4 + quad;
            #pragma unroll
            for (int mt = 0; mt < 4; ++mt) {
                int row = mt*16 + lane15;
                bf[mt] = *(const short8*)(hid + row * 256 + ((chunk ^ (row & 15)) << 3));
            }
            af = *(const short8*)(w2 + ((wave*8 + kblk)*64 + l) * 8);
            #pragma unroll
            for (int mt = 0; mt < 4; ++mt)
                acc[mt] = __builtin_amdgcn_mfma_f32_16x16x32_bf16(af, bf[mt], acc[mt], 0, 0, 0);
        }
        int n0 = wave*16 + quad*4;
        float4 bv = *(const float4*)(bias2 + 64 + n0);
        #pragma unroll
        for (int mt = 0; mt < 4; ++mt) {
            int m = mt*16 + lane15;
            if (m < valid) {
                float4 o;
                o.x = acc[mt][0] + bv.x; o.y = acc[mt][1] + bv.y;
                o.z = acc[mt][2] + bv.z; o.w = acc[mt][3] + bv.w;
                *(float4*)(out + (size_t)(r0 + m) * 64 + n0) = o;
            }
        }
    }
}

// ---------------------------------------------------------------------------
// Edge precompute: At[n] = f16(x_n @ ew1_top + eb1), Ab[n] = f16(x_n @ ew1_bot)
// for one batch. Reuses the w1e bf16 A-frags. Output rows 256 f16 = 512 B,
// staged through LDS for coalesced stores.
// ---------------------------------------------------------------------------
__global__ __launch_bounds__(256) void edge_pre_kernel(
    const u16* __restrict__ xbf, const float* __restrict__ eb1,
    const u16* __restrict__ frag, u16* __restrict__ At, u16* __restrict__ Ab,
    int b)
{
    __shared__ u16 xs[64 * 64];     // 8 KB input stage, mask 7
    __shared__ u16 stg[64 * 256];   // 32 KB f16 output stage, mask 7 (32 chunks/row)
    const int t = threadIdx.x;
    const int wave = t >> 6, l = t & 63, lane15 = l & 15, quad = l >> 4;
    const int r0 = blockIdx.x * 64;
    const int valid = min(64, NN - r0);

    #pragma unroll
    for (int it = 0; it < 2; ++it) {
        int i = t + it * 256;          // 0..511
        int m = i >> 3, c = i & 7;
        int row = min(r0 + m, NN - 1);
        uint4 q = ((const uint4*)xbf)[((size_t)(b * NN + row)) * 8 + c];
        *(uint4*)(xs + m * 64 + ((c ^ (m & 7)) << 3)) = q;
    }
    __syncthreads();

    const u16* w1 = frag;    // [16 ntile][4 kblk][64][8]; kblk 0-1 = top, 2-3 = bot
    for (int T = 0; T < 2; ++T) {
        f32x4 acc[4][4];
        #pragma unroll
        for (int i = 0; i < 4; ++i)
            #pragma unroll
            for (int mt = 0; mt < 4; ++mt) acc[i][mt] = f32x4{0.f,0.f,0.f,0.f};
        #pragma unroll
        for (int kblk = 0; kblk < 2; ++kblk) {
            short8 bf[4], af[4];
            int chunk = kblk * 4 + quad;
            #pragma unroll
            for (int mt = 0; mt < 4; ++mt) {
                int row = mt*16 + lane15;
                bf[mt] = *(const short8*)(xs + row * 64 + ((chunk ^ (row & 7)) << 3));
            }
            #pragma unroll
            for (int i = 0; i < 4; ++i)
                af[i] = *(const short8*)(w1 + (((wave*4 + i)*4 + T*2 + kblk)*64 + l) * 8);
            #pragma unroll
            for (int i = 0; i < 4; ++i)
                #pragma unroll
                for (int mt = 0; mt < 4; ++mt)
                    acc[i][mt] = __builtin_amdgcn_mfma_f32_16x16x32_bf16(af[i], bf[mt], acc[i][mt], 0, 0, 0);
        }
        // epilogue -> stg (f16), 16B chunk index c16 = ntile*2 + (quad>>1)
        #pragma unroll
        for (int i = 0; i < 4; ++i) {
            int ntile = wave*4 + i;
            int n0 = ntile*16 + quad*4;
            float4 bv;
            if (T == 0) bv = *(const float4*)(eb1 + n0);
            else        bv = make_float4(0.f, 0.f, 0.f, 0.f);
            int c16 = ntile*2 + (quad >> 1);
            #pragma unroll
            for (int mt = 0; mt < 4; ++mt) {
                int row = mt*16 + lane15;
                uint2 q = make_uint2(
                    pack_h2(acc[i][mt][0] + bv.x, acc[i][mt][1] + bv.y),
                    pack_h2(acc[i][mt][2] + bv.z, acc[i][mt][3] + bv.w));
                *(uint2*)(stg + row * 256 + ((c16 ^ (row & 7)) << 3) + (quad & 1) * 4) = q;
            }
        }
        __syncthreads();
        u16* dst = (T == 0) ? At : Ab;
        #pragma unroll
        for (int it = 0; it < 8; ++it) {
            int i = t + it * 256;          // 0..2047
            int m = i >> 5, c = i & 31;
            if (m < valid)
                ((uint4*)dst)[((size_t)(r0 + m)) * 32 + c] =
                    *(const uint4*)(stg + m * 256 + ((c ^ (m & 7)) << 3));
        }
        __syncthreads();   // stg reuse for T=1
    }
}

// ---------------------------------------------------------------------------
// Edge combine + GEMM2: hid_e = relu(At[u] + Ab[v]) (f16, pk ops), then
// fused W2' GEMM (f16 MFMA) -> one bf16 row per edge in perm[e].
// ---------------------------------------------------------------------------
__global__ __launch_bounds__(256) void edge_emb2_kernel(
    const u16* __restrict__ At, const u16* __restrict__ Ab,
    const int* __restrict__ edges, const float* __restrict__ bias2,
    const u16* __restrict__ frag, u16* __restrict__ perm)
{
    __shared__ u16 hid[64 * 256];   // 32 KB f16, 32 chunks/row, mask 15
    __shared__ int us[64], vs[64];
    const int t = threadIdx.x;
    const int wave = t >> 6, l = t & 63, lane15 = l & 15, quad = l >> 4;
    const int e0 = blockIdx.x * 64;
    const int valid = min(64, NE - e0);

    if (t < 64) {
        int e = min(e0 + t, NE - 1);
        us[t] = edges[2 * e];
        vs[t] = edges[2 * e + 1];
    }
    __syncthreads();

    // combine: 64 edges x 32 chunks of 16B; 8 chunks/thread
    #pragma unroll
    for (int it = 0; it < 8; ++it) {
        int i = t + it * 256;           // 0..2047
        int m = i >> 5, c = i & 31;
        int u = us[m], v = vs[m];
        uint4 a = ((const uint4*)At)[(size_t)((u32)u * 32 + c)];
        uint4 bq = ((const uint4*)Ab)[(size_t)((u32)v * 32 + c)];
        uint4 r;
        r.x = pk_relu_h2(pk_add_h2(a.x, bq.x));
        r.y = pk_relu_h2(pk_add_h2(a.y, bq.y));
        r.z = pk_relu_h2(pk_add_h2(a.z, bq.z));
        r.w = pk_relu_h2(pk_add_h2(a.w, bq.w));
        *(uint4*)(hid + m * 256 + ((c ^ (m & 15)) << 3)) = r;
    }
    __syncthreads();

    // fused GEMM2^T: N=64, K=256, f16 MFMA
    f32x4 acc[4];
    #pragma unroll
    for (int mt = 0; mt < 4; ++mt) acc[mt] = f32x4{0.f,0.f,0.f,0.f};
    const u16* w2 = frag + 49152;    // [4][8][64][8] f16, ntile = wave
    #pragma unroll
    for (int kblk = 0; kblk < 8; ++kblk) {
        short8 bf[4], af;
        int chunk = kblk * 4 + quad;
        #pragma unroll
        for (int mt = 0; mt < 4; ++mt) {
            int row = mt*16 + lane15;
            bf[mt] = *(const short8*)(hid + row * 256 + ((chunk ^ (row & 15)) << 3));
        }
        af = *(const short8*)(w2 + ((wave*8 + kblk)*64 + l) * 8);
        #pragma unroll
        for (int mt = 0; mt < 4; ++mt)
            acc[mt] = __builtin_amdgcn_mfma_f32_16x16x32_f16(as_h8(af), as_h8(bf[mt]), acc[mt], 0, 0, 0);
    }
    __syncthreads();   // all GEMM2 LDS reads done; reuse hid[0..8KB) as row stage

    {
        int n0 = wave*16 + quad*4;
        int chunk = wave*2 + (quad >> 1);    // 8 chunks/row, mask 7
        float4 bv = *(const float4*)(bias2 + n0);
        #pragma unroll
        for (int mt = 0; mt < 4; ++mt) {
            int m = mt*16 + lane15;
            uint2 q = make_uint2(
                pack_bf(acc[mt][0] + bv.x, acc[mt][1] + bv.y),
                pack_bf(acc[mt][2] + bv.z, acc[mt][3] + bv.w));
            *(uint2*)(hid + m * 64 + ((chunk ^ (m & 7)) << 3) + (quad & 1) * 4) = q;
        }
    }
    __syncthreads();

    // store: one 128B bf16 row per edge, block-contiguous in perm
    #pragma unroll
    for (int it = 0; it < 2; ++it) {
        int i = t + it * 256;          // 0..511
        int m = i >> 3, c8 = i & 7;
        if (m < valid)
            ((uint4*)perm)[((size_t)(e0 + m)) * 8 + c8] =
                *(const uint4*)(hid + m * 64 + ((c8 ^ (m & 7)) << 3));
    }
}

// ---------------------------------------------------------------------------
// Gather (streaming): out[b][n][:] += sum over slots [off[n], off[n+1]) of
// perm[eidx[slot]]. One wave per node, 2x4 rows per iteration.
// ---------------------------------------------------------------------------
__global__ __launch_bounds__(256) void gather2_kernel(
    const u32* __restrict__ perm32, const int* __restrict__ off,
    const int* __restrict__ eidx, float* __restrict__ out, int b)
{
    const int t = threadIdx.x, wave = t >> 6, l = t & 63;
    const int n = blockIdx.x * 4 + wave;
    const int base = off[n], cnt = off[n + 1] - base;
    if (cnt == 0) return;                   // wave-uniform
    const int slot = l >> 4, c8h = l & 15;  // row-in-group, 8B col
    float a0 = 0.f, a1 = 0.f, a2 = 0.f, a3 = 0.f;
    for (int j0 = 0; j0 < cnt; j0 += 8) {
        int jA = j0 + slot, jB = j0 + 4 + slot;
        int eA = eidx[base + min(jA, cnt - 1)];
        int eB = eidx[base + min(jB, cnt - 1)];
        const u32* rpA = perm32 + (size_t)eA * 32 + 2 * c8h;
        const u32* rpB = perm32 + (size_t)eB * 32 + 2 * c8h;
        u32 wA0 = rpA[0], wA1 = rpA[1];
        u32 wB0 = rpB[0], wB1 = rpB[1];
        union { u32 u; float f; } x0, x1, x2, x3;
        if (jA < cnt) {
            x0.u = wA0 << 16; x1.u = wA0 & 0xffff0000u;
            x2.u = wA1 << 16; x3.u = wA1 & 0xffff0000u;
            a0 += x0.f; a1 += x1.f; a2 += x2.f; a3 += x3.f;
        }
        if (jB < cnt) {
            x0.u = wB0 << 16; x1.u = wB0 & 0xffff0000u;
            x2.u = wB1 << 16; x3.u = wB1 & 0xffff0000u;
            a0 += x0.f; a1 += x1.f; a2 += x2.f; a3 += x3.f;
        }
    }
    a0 += __shfl_xor(a0, 16); a1 += __shfl_xor(a1, 16);
    a2 += __shfl_xor(a2, 16); a3 += __shfl_xor(a3, 16);
    a0 += __shfl_xor(a0, 32); a1 += __shfl_xor(a1, 32);
    a2 += __shfl_xor(a2, 32); a3 += __shfl_xor(a3, 32);
    if (l < 16) {
        float4* p = (float4*)(out + (size_t)(b * NN + n) * 64 + 4 * l);
        float4 h = *p;
        h.x += a0; h.y += a1; h.z += a2; h.w += a3;
        *p = h;
    }
}

// ---------------------------------------------------------------------------
extern "C" void kernel_launch(void* const* d_in, const int* in_sizes, int n_in,
                              void* d_out, int out_size, void* d_ws, size_t ws_size,
                              hipStream_t stream) {
    const float* x     = (const float*)d_in[0];
    const int*   edges = (const int*)d_in[1];
    const float* ew1   = (const float*)d_in[2];
    const float* eb1   = (const float*)d_in[3];
    const float* ew2   = (const float*)d_in[4];
    const float* eb2   = (const float*)d_in[5];
    const float* nw1   = (const float*)d_in[6];
    const float* nb1   = (const float*)d_in[7];
    const float* nw2   = (const float*)d_in[8];
    const float* nb2   = (const float*)d_in[9];
    const float* dw    = (const float*)d_in[10];
    const float* db    = (const float*)d_in[11];
    float* out = (float*)d_out;    // [BN][64]

    // Workspace layout (512B aligned)
    char* w = (char*)d_ws;
    size_t o = 0;
    auto take = [&](size_t bytes) { char* p = w + o; o = (o + bytes + 511) & ~(size_t)511; return p; };
    u16*   frag   = (u16*)  take(81920 * 2);               // 160 KB
    float* bias2  = (float*)take(128 * 4);
    int*   cursor = (int*)  take((size_t)NN * 4);          // 200 KB
    int*   off    = (int*)  take((size_t)(NN + 1) * 4);    // 200 KB
    int*   bsum   = (int*)  take((size_t)(NSB + 1) * 4);
    int*   boff   = (int*)  take((size_t)(NSB + 1) * 4);
    int*   eidx   = (int*)  take((size_t)2 * NE * 4);      // 4 MB
    u16*   xbf    = (u16*)  take((size_t)BN * 64 * 2);     // 12.8 MB
    u16*   At     = (u16*)  take((size_t)NN * 256 * 2);    // 25.6 MB
    u16*   Ab     = (u16*)  take((size_t)NN * 256 * 2);    // 25.6 MB
    u16*   perm   = (u16*)  take((size_t)NE * 64 * 2);     // 64 MB

    // CSR build (edges batch-invariant)
    csr_zero<<<NSB, 256, 0, stream>>>(cursor);
    csr_hist<<<(NE + 255) / 256, 256, 0, stream>>>(edges, cursor);
    scan_pass1<<<NSB, 256, 0, stream>>>(cursor, bsum);
    scan_pass2<<<1, 256, 0, stream>>>(bsum, boff);
    scan_pass3<<<NSB, 256, 0, stream>>>(cursor, boff, off);
    csr_fill<<<(NE + 255) / 256, 256, 0, stream>>>(edges, cursor, eidx);

    // Weight prep (one dispatch)
    weight_prep<<<321, 256, 0, stream>>>(ew1, nw1, ew2, nw2, dw, db, eb2, nb2, frag, bias2);

    // Node term -> out base (also produces xbf for the edge path)
    node_mlp_kernel<<<(BN + 63) / 64, 256, 0, stream>>>(x, nb1, bias2, frag, xbf, out);

    // Edge term per batch: per-node W1 halves -> combine+GEMM2 -> segmented sum
    for (int b = 0; b < BB; ++b) {
        edge_pre_kernel<<<(NN + 63) / 64, 256, 0, stream>>>(xbf, eb1, frag, At, Ab, b);
        edge_emb2_kernel<<<(NE + 63) / 64, 256, 0, stream>>>(At, Ab, edges, bias2, frag, perm);
        gather2_kernel<<<NN / 4, 256, 0, stream>>>((const u32*)perm, off, eidx, out, b);
    }
}

// Round 4
// 457.456 us; speedup vs baseline: 1.1118x; 1.1118x over previous
//
#include <hip/hip_runtime.h>
#include <hip/hip_bf16.h>

// Problem constants
#define BB   2
#define NN   50000
#define BN   100000     // B*N
#define NE   500000
#define NSB  196        // scan blocks = ceil(NN/256)

using u16 = unsigned short;
using u32 = unsigned int;
typedef __attribute__((ext_vector_type(8))) short short8;      // 8 x bf16/f16 bits
typedef __attribute__((ext_vector_type(8))) _Float16 half8;    // 8 x f16 (4 VGPRs)
typedef __attribute__((ext_vector_type(4))) float f32x4;       // MFMA accumulator

__device__ __forceinline__ u16 f2bf(float f) {   // RNE f32 -> bf16 (finite inputs)
    union { float f; u32 u; } w; w.f = f;
    return (u16)((w.u + 0x7fffu + ((w.u >> 16) & 1u)) >> 16);
}
__device__ __forceinline__ u16 f2h(float f) {    // RNE f32 -> f16
    _Float16 h = (_Float16)f; u16 u; __builtin_memcpy(&u, &h, 2); return u;
}

#if defined(__has_builtin)
#if __has_builtin(__builtin_amdgcn_cvt_pk_bf16_f32)
#define HAVE_CVTPK 1
#endif
#if __has_builtin(__builtin_amdgcn_cvt_pkrtz)
#define HAVE_PKRTZ 1
#endif
#endif

__device__ __forceinline__ u32 pack_bf(float lo, float hi) {
#ifdef HAVE_CVTPK
    auto r = __builtin_amdgcn_cvt_pk_bf16_f32(lo, hi);
    u32 out; __builtin_memcpy(&out, &r, sizeof(out));
    return out;
#else
    return ((u32)f2bf(hi) << 16) | (u32)f2bf(lo);
#endif
}

__device__ __forceinline__ u32 pack_h2(float lo, float hi) {
#ifdef HAVE_PKRTZ
    auto r = __builtin_amdgcn_cvt_pkrtz(lo, hi);
    u32 out; __builtin_memcpy(&out, &r, sizeof(out));
    return out;
#else
    return ((u32)f2h(hi) << 16) | (u32)f2h(lo);
#endif
}

__device__ __forceinline__ u32 pk_add_h2(u32 a, u32 b) {
    u32 d; asm("v_pk_add_f16 %0, %1, %2" : "=v"(d) : "v"(a), "v"(b)); return d;
}
__device__ __forceinline__ u32 pk_relu_h2(u32 a) {
    u32 d, z = 0u;
    asm("v_pk_max_f16 %0, %1, %2" : "=v"(d) : "v"(a), "v"(z)); return d;
}
__device__ __forceinline__ half8 as_h8(short8 s) {
    half8 h; __builtin_memcpy(&h, &s, 16); return h;
}

// ---------------------------------------------------------------------------
// Dual CSR build:
//   u-CSR: uoff[n], ueidx[slot] = edge id (edges sorted by u endpoint);
//          upos[e] = u-sorted slot of edge e (where its row lands in perm).
//   v-CSR: voff[n], vmap[slot] = u-sorted slot of the edge (perm row index).
// ---------------------------------------------------------------------------
__global__ __launch_bounds__(256) void csr_zero2(int* __restrict__ a, int* __restrict__ b) {
    int i = blockIdx.x * 256 + threadIdx.x;
    if (i < NN) { a[i] = 0; b[i] = 0; }
}

__global__ __launch_bounds__(256) void csr_hist2(const int* __restrict__ edges,
                                                 int* __restrict__ curU,
                                                 int* __restrict__ curV) {
    int e = blockIdx.x * 256 + threadIdx.x;
    if (e < NE) {
        atomicAdd(&curU[edges[2*e]], 1);
        atomicAdd(&curV[edges[2*e+1]], 1);
    }
}

__global__ __launch_bounds__(256) void scan_pass1(const int* __restrict__ cursor,
                                                  int* __restrict__ bsum) {
    __shared__ int s[256];
    const int t = threadIdx.x;
    int i = blockIdx.x * 256 + t;
    s[t] = (i < NN) ? cursor[i] : 0;
    __syncthreads();
    for (int d = 128; d > 0; d >>= 1) {
        if (t < d) s[t] += s[t + d];
        __syncthreads();
    }
    if (t == 0) bsum[blockIdx.x] = s[0];
}

__global__ __launch_bounds__(256) void scan_pass2(const int* __restrict__ bsum,
                                                  int* __restrict__ boff) {
    __shared__ int s[256];
    const int t = threadIdx.x;
    s[t] = (t < NSB) ? bsum[t] : 0;
    __syncthreads();
    for (int d = 1; d < 256; d <<= 1) {
        int v = (t >= d) ? s[t - d] : 0;
        __syncthreads();
        s[t] += v;
        __syncthreads();
    }
    if (t <= NSB) boff[t] = (t == 0) ? 0 : s[t - 1];
}

__global__ __launch_bounds__(256) void scan_pass3(int* __restrict__ cursor,
                                                  const int* __restrict__ boff,
                                                  int* __restrict__ off) {
    __shared__ int s[256];
    const int t = threadIdx.x;
    int i = blockIdx.x * 256 + t;
    int v = (i < NN) ? cursor[i] : 0;
    s[t] = v;
    __syncthreads();
    for (int d = 1; d < 256; d <<= 1) {
        int p = (t >= d) ? s[t - d] : 0;
        __syncthreads();
        s[t] += p;
        __syncthreads();
    }
    int excl = boff[blockIdx.x] + s[t] - v;
    if (i < NN) { off[i] = excl; cursor[i] = excl; }
    if (i == NN - 1) off[NN] = excl + v;
}

__global__ __launch_bounds__(256) void csr_fillU(const int* __restrict__ edges,
                                                 int* __restrict__ curU,
                                                 int* __restrict__ ueidx,
                                                 int* __restrict__ upos) {
    int e = blockIdx.x * 256 + threadIdx.x;
    if (e < NE) {
        int s = atomicAdd(&curU[edges[2*e]], 1);
        ueidx[s] = e;
        upos[e] = s;
    }
}

__global__ __launch_bounds__(256) void csr_fillV(const int* __restrict__ edges,
                                                 int* __restrict__ curV,
                                                 const int* __restrict__ upos,
                                                 int* __restrict__ vmap) {
    int e = blockIdx.x * 256 + threadIdx.x;
    if (e < NE) {
        int s = atomicAdd(&curV[edges[2*e+1]], 1);
        vmap[s] = upos[e];
    }
}

// ---------------------------------------------------------------------------
// Unified weight prep: blocks 0..191 swizzle w1 (A-frag layout, bf16),
// 192..319 compute fused W2' = W2@dw into A-frag (ew2 region in F16 for the
// f16 edge GEMM2; nw2 region stays bf16), block 320 fuses biases.
// Regions (u16): w1e @0 ([16][4][64][8]), w1n @32768 ([16][2][64][8]),
//                w2e' @49152 ([4][8][64][8], f16), w2n' @65536 ([4][8][64][8]).
// ---------------------------------------------------------------------------
__global__ __launch_bounds__(256) void weight_prep(
    const float* __restrict__ ew1, const float* __restrict__ nw1,
    const float* __restrict__ ew2, const float* __restrict__ nw2,
    const float* __restrict__ dw,  const float* __restrict__ db,
    const float* __restrict__ eb2, const float* __restrict__ nb2,
    u16* __restrict__ frag, float* __restrict__ bias2)
{
    int blk = blockIdx.x, t = threadIdx.x;
    if (blk < 192) {
        int idx = blk * 256 + t;                 // 0..49151
        const float* src; int KB, local;
        if (idx < 32768) { local = idx;         src = ew1; KB = 4; }
        else             { local = idx - 32768; src = nw1; KB = 2; }
        int j = local & 7, l = (local >> 3) & 63, rest = local >> 9;
        int kblk = rest % KB, ntile = rest / KB;
        int n = ntile * 16 + (l & 15);
        int k = kblk * 32 + ((l >> 4) << 3) + j;
        frag[idx] = f2bf(src[k * 256 + n]);
    } else if (blk < 320) {
        int idx = (blk - 192) * 256 + t;         // 0..32767
        bool is_e = (idx < 16384);
        const float* src = is_e ? ew2 : nw2;
        int local = idx & 16383;
        int j = local & 7, l = (local >> 3) & 63, rest = local >> 9;
        int kblk = rest & 7, ntile = rest >> 3;
        int n = ntile * 16 + (l & 15);
        int k = kblk * 32 + ((l >> 4) << 3) + j;
        float s = 0.f;
        for (int jj = 0; jj < 128; ++jj) s = fmaf(src[k * 128 + jj], dw[jj * 64 + n], s);
        frag[49152 + idx] = is_e ? f2h(s) : f2bf(s);
    } else if (t < 128) {
        int d = t & 63;
        const float* bsrc = (t >= 64) ? nb2 : eb2;
        float s = 0.f;
        #pragma unroll 4
        for (int j = 0; j < 128; ++j) s = fmaf(bsrc[j], dw[j * 64 + d], s);
        if (t >= 64) bias2[64 + d] = s + db[d];
        else         bias2[d] = s;
    }
}

// ---------------------------------------------------------------------------
// Node MLP (dw-fused) + x f32->bf16 conversion. (unchanged)
// ---------------------------------------------------------------------------
__global__ __launch_bounds__(256) void node_mlp_kernel(
    const float* __restrict__ x, const float* __restrict__ nb1,
    const float* __restrict__ bias2, const u16* __restrict__ frag,
    u16* __restrict__ xbf, float* __restrict__ out)
{
    __shared__ u16 xs[64 * 64];     // 8 KB, 8 chunks/row, swizzle mask 7
    __shared__ u16 hid[64 * 256];   // 32 KB, 32 chunks/row, swizzle mask 15
    const int t = threadIdx.x;
    const int wave = t >> 6, l = t & 63, lane15 = l & 15, quad = l >> 4;
    const int r0 = blockIdx.x * 64;
    const int valid = min(64, BN - r0);

    #pragma unroll
    for (int it = 0; it < 4; ++it) {
        int i = t + it * 256;          // 0..1023
        int m = i >> 4, c4 = i & 15;   // row, float4-col (8B half-chunk)
        int row = min(r0 + m, BN - 1);
        float4 g = ((const float4*)x)[(size_t)row * 16 + c4];
        uint2 q = make_uint2(pack_bf(g.x, g.y), pack_bf(g.z, g.w));
        int chunk = c4 >> 1;
        *(uint2*)(xs + m * 64 + ((chunk ^ (m & 7)) << 3) + (c4 & 1) * 4) = q;
        *(uint2*)(xbf + (size_t)row * 64 + c4 * 4) = q;
    }
    __syncthreads();

    {   // GEMM1^T, K=64
        f32x4 acc[4][4];
        #pragma unroll
        for (int i = 0; i < 4; ++i)
            #pragma unroll
            for (int mt = 0; mt < 4; ++mt) acc[i][mt] = f32x4{0.f,0.f,0.f,0.f};
        const u16* w1 = frag + 32768;    // [16][2][64][8]
        #pragma unroll
        for (int kblk = 0; kblk < 2; ++kblk) {
            short8 bf[4], af[4];
            int chunk = kblk * 4 + quad;
            #pragma unroll
            for (int mt = 0; mt < 4; ++mt) {
                int row = mt*16 + lane15;
                bf[mt] = *(const short8*)(xs + row * 64 + ((chunk ^ (row & 7)) << 3));
            }
            #pragma unroll
            for (int i = 0; i < 4; ++i)
                af[i] = *(const short8*)(w1 + (((wave*4 + i)*2 + kblk)*64 + l) * 8);
            #pragma unroll
            for (int i = 0; i < 4; ++i)
                #pragma unroll
                for (int mt = 0; mt < 4; ++mt)
                    acc[i][mt] = __builtin_amdgcn_mfma_f32_16x16x32_bf16(af[i], bf[mt], acc[i][mt], 0, 0, 0);
        }
        #pragma unroll
        for (int i = 0; i < 4; ++i) {
            int n0 = (wave*4 + i)*16 + quad*4;
            int chunk = (wave*4 + i)*2 + (quad >> 1);
            float4 bv = *(const float4*)(nb1 + n0);
            #pragma unroll
            for (int mt = 0; mt < 4; ++mt) {
                int row = mt*16 + lane15;
                uint2 q = make_uint2(
                    pack_bf(fmaxf(acc[i][mt][0] + bv.x, 0.f), fmaxf(acc[i][mt][1] + bv.y, 0.f)),
                    pack_bf(fmaxf(acc[i][mt][2] + bv.z, 0.f), fmaxf(acc[i][mt][3] + bv.w, 0.f)));
                *(uint2*)(hid + row * 256 + ((chunk ^ (row & 15)) << 3) + (quad & 1) * 4) = q;
            }
        }
    }
    __syncthreads();

    {   // fused GEMM2^T: N=64, K=256 -> f32 out
        f32x4 acc[4];
        #pragma unroll
        for (int mt = 0; mt < 4; ++mt) acc[mt] = f32x4{0.f,0.f,0.f,0.f};
        const u16* w2 = frag + 65536;    // [4][8][64][8], ntile = wave
        #pragma unroll
        for (int kblk = 0; kblk < 8; ++kblk) {
            short8 bf[4], af;
            int chunk = kblk * 4 + quad;
            #pragma unroll
            for (int mt = 0; mt < 4; ++mt) {
                int row = mt*16 + lane15;
                bf[mt] = *(const short8*)(hid + row * 256 + ((chunk ^ (row & 15)) << 3));
            }
            af = *(const short8*)(w2 + ((wave*8 + kblk)*64 + l) * 8);
            #pragma unroll
            for (int mt = 0; mt < 4; ++mt)
                acc[mt] = __builtin_amdgcn_mfma_f32_16x16x32_bf16(af, bf[mt], acc[mt], 0, 0, 0);
        }
        int n0 = wave*16 + quad*4;
        float4 bv = *(const float4*)(bias2 + 64 + n0);
        #pragma unroll
        for (int mt = 0; mt < 4; ++mt) {
            int m = mt*16 + lane15;
            if (m < valid) {
                float4 o;
                o.x = acc[mt][0] + bv.x; o.y = acc[mt][1] + bv.y;
                o.z = acc[mt][2] + bv.z; o.w = acc[mt][3] + bv.w;
                *(float4*)(out + (size_t)(r0 + m) * 64 + n0) = o;
            }
        }
    }
}

// ---------------------------------------------------------------------------
// Edge precompute: At[n] = f16(x_n @ ew1_top + eb1), Ab[n] = f16(x_n @ ew1_bot)
// for one batch. Reuses the w1e bf16 A-frags.
// ---------------------------------------------------------------------------
__global__ __launch_bounds__(256) void edge_pre_kernel(
    const u16* __restrict__ xbf, const float* __restrict__ eb1,
    const u16* __restrict__ frag, u16* __restrict__ At, u16* __restrict__ Ab,
    int b)
{
    __shared__ u16 xs[64 * 64];     // 8 KB input stage, mask 7
    __shared__ u16 stg[64 * 256];   // 32 KB f16 output stage, mask 7 (32 chunks/row)
    const int t = threadIdx.x;
    const int wave = t >> 6, l = t & 63, lane15 = l & 15, quad = l >> 4;
    const int r0 = blockIdx.x * 64;
    const int valid = min(64, NN - r0);

    #pragma unroll
    for (int it = 0; it < 2; ++it) {
        int i = t + it * 256;          // 0..511
        int m = i >> 3, c = i & 7;
        int row = min(r0 + m, NN - 1);
        uint4 q = ((const uint4*)xbf)[((size_t)(b * NN + row)) * 8 + c];
        *(uint4*)(xs + m * 64 + ((c ^ (m & 7)) << 3)) = q;
    }
    __syncthreads();

    const u16* w1 = frag;    // [16 ntile][4 kblk][64][8]; kblk 0-1 = top, 2-3 = bot
    for (int T = 0; T < 2; ++T) {
        f32x4 acc[4][4];
        #pragma unroll
        for (int i = 0; i < 4; ++i)
            #pragma unroll
            for (int mt = 0; mt < 4; ++mt) acc[i][mt] = f32x4{0.f,0.f,0.f,0.f};
        #pragma unroll
        for (int kblk = 0; kblk < 2; ++kblk) {
            short8 bf[4], af[4];
            int chunk = kblk * 4 + quad;
            #pragma unroll
            for (int mt = 0; mt < 4; ++mt) {
                int row = mt*16 + lane15;
                bf[mt] = *(const short8*)(xs + row * 64 + ((chunk ^ (row & 7)) << 3));
            }
            #pragma unroll
            for (int i = 0; i < 4; ++i)
                af[i] = *(const short8*)(w1 + (((wave*4 + i)*4 + T*2 + kblk)*64 + l) * 8);
            #pragma unroll
            for (int i = 0; i < 4; ++i)
                #pragma unroll
                for (int mt = 0; mt < 4; ++mt)
                    acc[i][mt] = __builtin_amdgcn_mfma_f32_16x16x32_bf16(af[i], bf[mt], acc[i][mt], 0, 0, 0);
        }
        #pragma unroll
        for (int i = 0; i < 4; ++i) {
            int ntile = wave*4 + i;
            int n0 = ntile*16 + quad*4;
            float4 bv;
            if (T == 0) bv = *(const float4*)(eb1 + n0);
            else        bv = make_float4(0.f, 0.f, 0.f, 0.f);
            int c16 = ntile*2 + (quad >> 1);
            #pragma unroll
            for (int mt = 0; mt < 4; ++mt) {
                int row = mt*16 + lane15;
                uint2 q = make_uint2(
                    pack_h2(acc[i][mt][0] + bv.x, acc[i][mt][1] + bv.y),
                    pack_h2(acc[i][mt][2] + bv.z, acc[i][mt][3] + bv.w));
                *(uint2*)(stg + row * 256 + ((c16 ^ (row & 7)) << 3) + (quad & 1) * 4) = q;
            }
        }
        __syncthreads();
        u16* dst = (T == 0) ? At : Ab;
        #pragma unroll
        for (int it = 0; it < 8; ++it) {
            int i = t + it * 256;          // 0..2047
            int m = i >> 5, c = i & 31;
            if (m < valid)
                ((uint4*)dst)[((size_t)(r0 + m)) * 32 + c] =
                    *(const uint4*)(stg + m * 256 + ((c ^ (m & 7)) << 3));
        }
        __syncthreads();   // stg reuse for T=1
    }
}

// ---------------------------------------------------------------------------
// Edge combine + GEMM2 over u-SORTED edges: hid = relu(At[u] + Ab[v]) (f16),
// fused W2' GEMM (f16 MFMA) -> one bf16 row per edge at its u-sorted slot.
// K split in two 128-halves (16 KB LDS) -> 8 blocks/CU for latency hiding.
// ---------------------------------------------------------------------------
__global__ __launch_bounds__(256) void edge_emb2_kernel(
    const u16* __restrict__ At, const u16* __restrict__ Ab,
    const int* __restrict__ edges, const int* __restrict__ ueidx,
    const float* __restrict__ bias2,
    const u16* __restrict__ frag, u16* __restrict__ perm)
{
    __shared__ u16 hid[64 * 128];   // 16 KB f16, 16 chunks/row, mask 15
    __shared__ int us[64], vs[64];
    const int t = threadIdx.x;
    const int wave = t >> 6, l = t & 63, lane15 = l & 15, quad = l >> 4;
    const int e0 = blockIdx.x * 64;
    const int valid = min(64, NE - e0);

    if (t < 64) {
        int j = min(e0 + t, NE - 1);
        int e = ueidx[j];
        us[t] = edges[2 * e];
        vs[t] = edges[2 * e + 1];
    }
    __syncthreads();

    f32x4 acc[4];
    #pragma unroll
    for (int mt = 0; mt < 4; ++mt) acc[mt] = f32x4{0.f,0.f,0.f,0.f};
    const u16* w2 = frag + 49152;    // [4 ntile][8 kblk][64][8] f16, ntile = wave

    #pragma unroll
    for (int half = 0; half < 2; ++half) {
        // combine: 64 edges x 16 chunks of 16B (K-half); 4 chunks/thread
        #pragma unroll
        for (int it = 0; it < 4; ++it) {
            int i = t + it * 256;           // 0..1023
            int m = i >> 4, c = i & 15;
            int cg = half * 16 + c;
            int u = us[m], v = vs[m];
            uint4 a = ((const uint4*)At)[(size_t)((u32)u) * 32 + cg];
            uint4 bq = ((const uint4*)Ab)[(size_t)((u32)v) * 32 + cg];
            uint4 r;
            r.x = pk_relu_h2(pk_add_h2(a.x, bq.x));
            r.y = pk_relu_h2(pk_add_h2(a.y, bq.y));
            r.z = pk_relu_h2(pk_add_h2(a.z, bq.z));
            r.w = pk_relu_h2(pk_add_h2(a.w, bq.w));
            *(uint4*)(hid + m * 128 + ((c ^ (m & 15)) << 3)) = r;
        }
        __syncthreads();

        // GEMM2^T quarter: N=64, K=128 (this half), f16 MFMA
        #pragma unroll
        for (int kb = 0; kb < 4; ++kb) {
            short8 bf[4], af;
            int chunk = kb * 4 + quad;      // local chunk 0..15
            #pragma unroll
            for (int mt = 0; mt < 4; ++mt) {
                int row = mt*16 + lane15;
                bf[mt] = *(const short8*)(hid + row * 128 + ((chunk ^ (row & 15)) << 3));
            }
            af = *(const short8*)(w2 + ((wave*8 + half*4 + kb)*64 + l) * 8);
            #pragma unroll
            for (int mt = 0; mt < 4; ++mt)
                acc[mt] = __builtin_amdgcn_mfma_f32_16x16x32_f16(as_h8(af), as_h8(bf[mt]), acc[mt], 0, 0, 0);
        }
        __syncthreads();   // hid reusable (next half / epilogue)
    }

    {   // epilogue: bf16 rows into hid[0..8KB), 8 chunks/row, mask 7
        int n0 = wave*16 + quad*4;
        int chunk = wave*2 + (quad >> 1);
        float4 bv = *(const float4*)(bias2 + n0);
        #pragma unroll
        for (int mt = 0; mt < 4; ++mt) {
            int m = mt*16 + lane15;
            uint2 q = make_uint2(
                pack_bf(acc[mt][0] + bv.x, acc[mt][1] + bv.y),
                pack_bf(acc[mt][2] + bv.z, acc[mt][3] + bv.w));
            *(uint2*)(hid + m * 64 + ((chunk ^ (m & 7)) << 3) + (quad & 1) * 4) = q;
        }
    }
    __syncthreads();

    // store: one 128B bf16 row per edge at its u-sorted slot (contiguous)
    #pragma unroll
    for (int it = 0; it < 2; ++it) {
        int i = t + it * 256;          // 0..511
        int m = i >> 3, c8 = i & 7;
        if (m < valid)
            ((uint4*)perm)[((size_t)(e0 + m)) * 8 + c8] =
                *(const uint4*)(hid + m * 64 + ((c8 ^ (m & 7)) << 3));
    }
}

// ---------------------------------------------------------------------------
// Combined gather: out[b][n][:] += sum(perm[uoff[n]..uoff[n+1])  (streaming)
//                               +  sum(perm[vmap[voff[n]..voff[n+1])]) (random)
// One wave per node, 2x4 rows in flight per iteration.
// ---------------------------------------------------------------------------
__global__ __launch_bounds__(256) void gather3_kernel(
    const u32* __restrict__ perm32, const int* __restrict__ uoff,
    const int* __restrict__ voff, const int* __restrict__ vmap,
    float* __restrict__ out, int b)
{
    const int t = threadIdx.x, wave = t >> 6, l = t & 63;
    const int n = blockIdx.x * 4 + wave;
    const int ub = uoff[n], ucnt = uoff[n + 1] - ub;
    const int vb = voff[n], vcnt = voff[n + 1] - vb;
    if ((ucnt | vcnt) == 0) return;         // wave-uniform
    const int slot = l >> 4, c8h = l & 15;  // row-in-group, 8B col
    float a0 = 0.f, a1 = 0.f, a2 = 0.f, a3 = 0.f;

    // u-run: contiguous rows
    for (int j0 = 0; j0 < ucnt; j0 += 8) {
        int jA = j0 + slot, jB = j0 + 4 + slot;
        const u32* rpA = perm32 + (size_t)(ub + min(jA, ucnt - 1)) * 32 + 2 * c8h;
        const u32* rpB = perm32 + (size_t)(ub + min(jB, ucnt - 1)) * 32 + 2 * c8h;
        u32 wA0 = rpA[0], wA1 = rpA[1];
        u32 wB0 = rpB[0], wB1 = rpB[1];
        union { u32 u; float f; } x0, x1, x2, x3;
        if (jA < ucnt) {
            x0.u = wA0 << 16; x1.u = wA0 & 0xffff0000u;
            x2.u = wA1 << 16; x3.u = wA1 & 0xffff0000u;
            a0 += x0.f; a1 += x1.f; a2 += x2.f; a3 += x3.f;
        }
        if (jB < ucnt) {
            x0.u = wB0 << 16; x1.u = wB0 & 0xffff0000u;
            x2.u = wB1 << 16; x3.u = wB1 & 0xffff0000u;
            a0 += x0.f; a1 += x1.f; a2 += x2.f; a3 += x3.f;
        }
    }
    // v-list: indirected rows
    for (int j0 = 0; j0 < vcnt; j0 += 8) {
        int jA = j0 + slot, jB = j0 + 4 + slot;
        int pA = vmap[vb + min(jA, vcnt - 1)];
        int pB = vmap[vb + min(jB, vcnt - 1)];
        const u32* rpA = perm32 + (size_t)pA * 32 + 2 * c8h;
        const u32* rpB = perm32 + (size_t)pB * 32 + 2 * c8h;
        u32 wA0 = rpA[0], wA1 = rpA[1];
        u32 wB0 = rpB[0], wB1 = rpB[1];
        union { u32 u; float f; } x0, x1, x2, x3;
        if (jA < vcnt) {
            x0.u = wA0 << 16; x1.u = wA0 & 0xffff0000u;
            x2.u = wA1 << 16; x3.u = wA1 & 0xffff0000u;
            a0 += x0.f; a1 += x1.f; a2 += x2.f; a3 += x3.f;
        }
        if (jB < vcnt) {
            x0.u = wB0 << 16; x1.u = wB0 & 0xffff0000u;
            x2.u = wB1 << 16; x3.u = wB1 & 0xffff0000u;
            a0 += x0.f; a1 += x1.f; a2 += x2.f; a3 += x3.f;
        }
    }

    a0 += __shfl_xor(a0, 16); a1 += __shfl_xor(a1, 16);
    a2 += __shfl_xor(a2, 16); a3 += __shfl_xor(a3, 16);
    a0 += __shfl_xor(a0, 32); a1 += __shfl_xor(a1, 32);
    a2 += __shfl_xor(a2, 32); a3 += __shfl_xor(a3, 32);
    if (l < 16) {
        float4* p = (float4*)(out + (size_t)(b * NN + n) * 64 + 4 * l);
        float4 h = *p;
        h.x += a0; h.y += a1; h.z += a2; h.w += a3;
        *p = h;
    }
}

// ---------------------------------------------------------------------------
extern "C" void kernel_launch(void* const* d_in, const int* in_sizes, int n_in,
                              void* d_out, int out_size, void* d_ws, size_t ws_size,
                              hipStream_t stream) {
    const float* x     = (const float*)d_in[0];
    const int*   edges = (const int*)d_in[1];
    const float* ew1   = (const float*)d_in[2];
    const float* eb1   = (const float*)d_in[3];
    const float* ew2   = (const float*)d_in[4];
    const float* eb2   = (const float*)d_in[5];
    const float* nw1   = (const float*)d_in[6];
    const float* nb1   = (const float*)d_in[7];
    const float* nw2   = (const float*)d_in[8];
    const float* nb2   = (const float*)d_in[9];
    const float* dw    = (const float*)d_in[10];
    const float* db    = (const float*)d_in[11];
    float* out = (float*)d_out;    // [BN][64]

    // Workspace layout (512B aligned)
    char* w = (char*)d_ws;
    size_t o = 0;
    auto take = [&](size_t bytes) { char* p = w + o; o = (o + bytes + 511) & ~(size_t)511; return p; };
    u16*   frag   = (u16*)  take(81920 * 2);               // 160 KB
    float* bias2  = (float*)take(128 * 4);
    int*   curU   = (int*)  take((size_t)NN * 4);          // 200 KB
    int*   curV   = (int*)  take((size_t)NN * 4);          // 200 KB
    int*   uoff   = (int*)  take((size_t)(NN + 1) * 4);    // 200 KB
    int*   voff   = (int*)  take((size_t)(NN + 1) * 4);    // 200 KB
    int*   bsum   = (int*)  take((size_t)(NSB + 1) * 4);
    int*   boff   = (int*)  take((size_t)(NSB + 1) * 4);
    int*   ueidx  = (int*)  take((size_t)NE * 4);          // 2 MB
    int*   upos   = (int*)  take((size_t)NE * 4);          // 2 MB
    int*   vmap   = (int*)  take((size_t)NE * 4);          // 2 MB
    u16*   xbf    = (u16*)  take((size_t)BN * 64 * 2);     // 12.8 MB
    u16*   At     = (u16*)  take((size_t)NN * 256 * 2);    // 25.6 MB
    u16*   Ab     = (u16*)  take((size_t)NN * 256 * 2);    // 25.6 MB
    u16*   perm   = (u16*)  take((size_t)NE * 64 * 2);     // 64 MB

    // Dual CSR build (edges batch-invariant)
    csr_zero2<<<NSB, 256, 0, stream>>>(curU, curV);
    csr_hist2<<<(NE + 255) / 256, 256, 0, stream>>>(edges, curU, curV);
    scan_pass1<<<NSB, 256, 0, stream>>>(curU, bsum);
    scan_pass2<<<1, 256, 0, stream>>>(bsum, boff);
    scan_pass3<<<NSB, 256, 0, stream>>>(curU, boff, uoff);
    scan_pass1<<<NSB, 256, 0, stream>>>(curV, bsum);
    scan_pass2<<<1, 256, 0, stream>>>(bsum, boff);
    scan_pass3<<<NSB, 256, 0, stream>>>(curV, boff, voff);
    csr_fillU<<<(NE + 255) / 256, 256, 0, stream>>>(edges, curU, ueidx, upos);
    csr_fillV<<<(NE + 255) / 256, 256, 0, stream>>>(edges, curV, upos, vmap);

    // Weight prep (one dispatch)
    weight_prep<<<321, 256, 0, stream>>>(ew1, nw1, ew2, nw2, dw, db, eb2, nb2, frag, bias2);

    // Node term -> out base (also produces xbf for the edge path)
    node_mlp_kernel<<<(BN + 63) / 64, 256, 0, stream>>>(x, nb1, bias2, frag, xbf, out);

    // Edge term per batch: per-node W1 halves -> combine+GEMM2 (u-sorted) -> gather
    for (int b = 0; b < BB; ++b) {
        edge_pre_kernel<<<(NN + 63) / 64, 256, 0, stream>>>(xbf, eb1, frag, At, Ab, b);
        edge_emb2_kernel<<<(NE + 63) / 64, 256, 0, stream>>>(At, Ab, edges, ueidx, bias2, frag, perm);
        gather3_kernel<<<NN / 4, 256, 0, stream>>>((const u32*)perm, uoff, voff, vmap, out, b);
    }
}

// Round 6
// 419.149 us; speedup vs baseline: 1.2134x; 1.0914x over previous
//
#include <hip/hip_runtime.h>
#include <hip/hip_bf16.h>

// Problem constants
#define BB   2
#define NN   50000
#define BN   100000     // B*N
#define NE   500000
#define NSB  196        // scan blocks = ceil(NN/256)

using u16 = unsigned short;
using u32 = unsigned int;
typedef __attribute__((ext_vector_type(8))) short short8;      // 8 x bf16/f16 bits
typedef __attribute__((ext_vector_type(8))) _Float16 half8;    // 8 x f16 (4 VGPRs)
typedef __attribute__((ext_vector_type(4))) float f32x4;       // MFMA accumulator

__device__ __forceinline__ u16 f2bf(float f) {   // RNE f32 -> bf16 (finite inputs)
    union { float f; u32 u; } w; w.f = f;
    return (u16)((w.u + 0x7fffu + ((w.u >> 16) & 1u)) >> 16);
}
__device__ __forceinline__ u16 f2h(float f) {    // RNE f32 -> f16
    _Float16 h = (_Float16)f; u16 u; __builtin_memcpy(&u, &h, 2); return u;
}

#if defined(__has_builtin)
#if __has_builtin(__builtin_amdgcn_cvt_pk_bf16_f32)
#define HAVE_CVTPK 1
#endif
#if __has_builtin(__builtin_amdgcn_cvt_pkrtz)
#define HAVE_PKRTZ 1
#endif
#endif

__device__ __forceinline__ u32 pack_bf(float lo, float hi) {
#ifdef HAVE_CVTPK
    auto r = __builtin_amdgcn_cvt_pk_bf16_f32(lo, hi);
    u32 out; __builtin_memcpy(&out, &r, sizeof(out));
    return out;
#else
    return ((u32)f2bf(hi) << 16) | (u32)f2bf(lo);
#endif
}

__device__ __forceinline__ u32 pack_h2(float lo, float hi) {
#ifdef HAVE_PKRTZ
    auto r = __builtin_amdgcn_cvt_pkrtz(lo, hi);
    u32 out; __builtin_memcpy(&out, &r, sizeof(out));
    return out;
#else
    return ((u32)f2h(hi) << 16) | (u32)f2h(lo);
#endif
}

__device__ __forceinline__ u32 pk_add_h2(u32 a, u32 b) {
    u32 d; asm("v_pk_add_f16 %0, %1, %2" : "=v"(d) : "v"(a), "v"(b)); return d;
}
__device__ __forceinline__ u32 pk_relu_h2(u32 a) {
    u32 d, z = 0u;
    asm("v_pk_max_f16 %0, %1, %2" : "=v"(d) : "v"(a), "v"(z)); return d;
}
__device__ __forceinline__ half8 as_h8(short8 s) {
    half8 h; __builtin_memcpy(&h, &s, 16); return h;
}

// ---------------------------------------------------------------------------
// Dual CSR build:
//   u-CSR: uoff[n]; uv[slot] = (u,v) of the edge at u-sorted slot;
//          upos[e] = u-sorted slot of edge e (its row index in perm).
//   v-CSR: voff[n], vmap[slot] = u-sorted slot (perm row index).
// ---------------------------------------------------------------------------
__global__ __launch_bounds__(256) void csr_zero2(int* __restrict__ a, int* __restrict__ b) {
    int i = blockIdx.x * 256 + threadIdx.x;
    if (i < NN) { a[i] = 0; b[i] = 0; }
}

__global__ __launch_bounds__(256) void csr_hist2(const int* __restrict__ edges,
                                                 int* __restrict__ curU,
                                                 int* __restrict__ curV) {
    int e = blockIdx.x * 256 + threadIdx.x;
    if (e < NE) {
        atomicAdd(&curU[edges[2*e]], 1);
        atomicAdd(&curV[edges[2*e+1]], 1);
    }
}

// y = 0 scans curU, y = 1 scans curV (bsum/boff regions of NSB+1 each)
__global__ __launch_bounds__(256) void scan_pass1d(const int* __restrict__ curU,
                                                   const int* __restrict__ curV,
                                                   int* __restrict__ bsum2) {
    __shared__ int s[256];
    const int t = threadIdx.x;
    const int* cursor = blockIdx.y ? curV : curU;
    int i = blockIdx.x * 256 + t;
    s[t] = (i < NN) ? cursor[i] : 0;
    __syncthreads();
    for (int d = 128; d > 0; d >>= 1) {
        if (t < d) s[t] += s[t + d];
        __syncthreads();
    }
    if (t == 0) bsum2[blockIdx.y * (NSB + 1) + blockIdx.x] = s[0];
}

__global__ __launch_bounds__(256) void scan_pass2d(const int* __restrict__ bsum2,
                                                   int* __restrict__ boff2) {
    __shared__ int s[256];
    const int t = threadIdx.x;
    const int base = blockIdx.y * (NSB + 1);
    s[t] = (t < NSB) ? bsum2[base + t] : 0;
    __syncthreads();
    for (int d = 1; d < 256; d <<= 1) {
        int v = (t >= d) ? s[t - d] : 0;
        __syncthreads();
        s[t] += v;
        __syncthreads();
    }
    if (t <= NSB) boff2[base + t] = (t == 0) ? 0 : s[t - 1];
}

__global__ __launch_bounds__(256) void scan_pass3d(int* __restrict__ curU,
                                                   int* __restrict__ curV,
                                                   const int* __restrict__ boff2,
                                                   int* __restrict__ uoff,
                                                   int* __restrict__ voff) {
    __shared__ int s[256];
    const int t = threadIdx.x;
    int* cursor = blockIdx.y ? curV : curU;
    int* off    = blockIdx.y ? voff : uoff;
    const int base = blockIdx.y * (NSB + 1);
    int i = blockIdx.x * 256 + t;
    int v = (i < NN) ? cursor[i] : 0;
    s[t] = v;
    __syncthreads();
    for (int d = 1; d < 256; d <<= 1) {
        int p = (t >= d) ? s[t - d] : 0;
        __syncthreads();
        s[t] += p;
        __syncthreads();
    }
    int excl = boff2[base + blockIdx.x] + s[t] - v;
    if (i < NN) { off[i] = excl; cursor[i] = excl; }
    if (i == NN - 1) off[NN] = excl + v;
}

__global__ __launch_bounds__(256) void csr_fillU(const int* __restrict__ edges,
                                                 int* __restrict__ curU,
                                                 int2* __restrict__ uv,
                                                 int* __restrict__ upos) {
    int e = blockIdx.x * 256 + threadIdx.x;
    if (e < NE) {
        int u = edges[2*e], v = edges[2*e+1];
        int s = atomicAdd(&curU[u], 1);
        uv[s] = make_int2(u, v);
        upos[e] = s;
    }
}

__global__ __launch_bounds__(256) void csr_fillV(const int* __restrict__ edges,
                                                 int* __restrict__ curV,
                                                 const int* __restrict__ upos,
                                                 int* __restrict__ vmap) {
    int e = blockIdx.x * 256 + threadIdx.x;
    if (e < NE) {
        int s = atomicAdd(&curV[edges[2*e+1]], 1);
        vmap[s] = upos[e];
    }
}

// ---------------------------------------------------------------------------
// Unified weight prep (unchanged layout):
// Regions (u16): w1e @0 ([16][4][64][8] bf16), w1n @32768 ([16][2][64][8] bf16),
//                w2e' @49152 ([4][8][64][8] f16), w2n' @65536 ([4][8][64][8] bf16).
// ---------------------------------------------------------------------------
__global__ __launch_bounds__(256) void weight_prep(
    const float* __restrict__ ew1, const float* __restrict__ nw1,
    const float* __restrict__ ew2, const float* __restrict__ nw2,
    const float* __restrict__ dw,  const float* __restrict__ db,
    const float* __restrict__ eb2, const float* __restrict__ nb2,
    u16* __restrict__ frag, float* __restrict__ bias2)
{
    int blk = blockIdx.x, t = threadIdx.x;
    if (blk < 192) {
        int idx = blk * 256 + t;                 // 0..49151
        const float* src; int KB, local;
        if (idx < 32768) { local = idx;         src = ew1; KB = 4; }
        else             { local = idx - 32768; src = nw1; KB = 2; }
        int j = local & 7, l = (local >> 3) & 63, rest = local >> 9;
        int kblk = rest % KB, ntile = rest / KB;
        int n = ntile * 16 + (l & 15);
        int k = kblk * 32 + ((l >> 4) << 3) + j;
        frag[idx] = f2bf(src[k * 256 + n]);
    } else if (blk < 320) {
        int idx = (blk - 192) * 256 + t;         // 0..32767
        bool is_e = (idx < 16384);
        const float* src = is_e ? ew2 : nw2;
        int local = idx & 16383;
        int j = local & 7, l = (local >> 3) & 63, rest = local >> 9;
        int kblk = rest & 7, ntile = rest >> 3;
        int n = ntile * 16 + (l & 15);
        int k = kblk * 32 + ((l >> 4) << 3) + j;
        float s = 0.f;
        for (int jj = 0; jj < 128; ++jj) s = fmaf(src[k * 128 + jj], dw[jj * 64 + n], s);
        frag[49152 + idx] = is_e ? f2h(s) : f2bf(s);
    } else if (t < 128) {
        int d = t & 63;
        const float* bsrc = (t >= 64) ? nb2 : eb2;
        float s = 0.f;
        #pragma unroll 4
        for (int j = 0; j < 128; ++j) s = fmaf(bsrc[j], dw[j * 64 + d], s);
        if (t >= 64) bias2[64 + d] = s + db[d];
        else         bias2[d] = s;
    }
}

// ---------------------------------------------------------------------------
// Node MLP (dw-fused). When emitAB != 0 it also computes the edge-MLP per-node
// halves At[rg] = f16(x_rg @ ew1_top + eb1), Ab[rg] = f16(x_rg @ ew1_bot) for
// ALL BN rows (At/Ab sized [BN][256]); xbf is skipped in that mode.
// ---------------------------------------------------------------------------
__global__ __launch_bounds__(256) void node_mlp_kernel(
    const float* __restrict__ x, const float* __restrict__ nb1,
    const float* __restrict__ eb1, const float* __restrict__ bias2,
    const u16* __restrict__ frag,
    u16* __restrict__ xbf, u16* __restrict__ At, u16* __restrict__ Ab,
    float* __restrict__ out, int emitAB)
{
    __shared__ u16 xs[64 * 64];     // 8 KB, 8 chunks/row, swizzle mask 7
    __shared__ u16 hid[64 * 256];   // 32 KB, reused as stg in the edge phase
    const int t = threadIdx.x;
    const int wave = t >> 6, l = t & 63, lane15 = l & 15, quad = l >> 4;
    const int r0 = blockIdx.x * 64;
    const int valid = min(64, BN - r0);

    #pragma unroll
    for (int it = 0; it < 4; ++it) {
        int i = t + it * 256;          // 0..1023
        int m = i >> 4, c4 = i & 15;   // row, float4-col (8B half-chunk)
        int row = min(r0 + m, BN - 1);
        float4 g = ((const float4*)x)[(size_t)row * 16 + c4];
        uint2 q = make_uint2(pack_bf(g.x, g.y), pack_bf(g.z, g.w));
        int chunk = c4 >> 1;
        *(uint2*)(xs + m * 64 + ((chunk ^ (m & 7)) << 3) + (c4 & 1) * 4) = q;
        if (!emitAB) *(uint2*)(xbf + (size_t)row * 64 + c4 * 4) = q;
    }
    __syncthreads();

    {   // GEMM1^T (node), K=64
        f32x4 acc[4][4];
        #pragma unroll
        for (int i = 0; i < 4; ++i)
            #pragma unroll
            for (int mt = 0; mt < 4; ++mt) acc[i][mt] = f32x4{0.f,0.f,0.f,0.f};
        const u16* w1 = frag + 32768;    // [16][2][64][8]
        #pragma unroll
        for (int kblk = 0; kblk < 2; ++kblk) {
            short8 bf[4], af[4];
            int chunk = kblk * 4 + quad;
            #pragma unroll
            for (int mt = 0; mt < 4; ++mt) {
                int row = mt*16 + lane15;
                bf[mt] = *(const short8*)(xs + row * 64 + ((chunk ^ (row & 7)) << 3));
            }
            #pragma unroll
            for (int i = 0; i < 4; ++i)
                af[i] = *(const short8*)(w1 + (((wave*4 + i)*2 + kblk)*64 + l) * 8);
            #pragma unroll
            for (int i = 0; i < 4; ++i)
                #pragma unroll
                for (int mt = 0; mt < 4; ++mt)
                    acc[i][mt] = __builtin_amdgcn_mfma_f32_16x16x32_bf16(af[i], bf[mt], acc[i][mt], 0, 0, 0);
        }
        #pragma unroll
        for (int i = 0; i < 4; ++i) {
            int n0 = (wave*4 + i)*16 + quad*4;
            int chunk = (wave*4 + i)*2 + (quad >> 1);
            float4 bv = *(const float4*)(nb1 + n0);
            #pragma unroll
            for (int mt = 0; mt < 4; ++mt) {
                int row = mt*16 + lane15;
                uint2 q = make_uint2(
                    pack_bf(fmaxf(acc[i][mt][0] + bv.x, 0.f), fmaxf(acc[i][mt][1] + bv.y, 0.f)),
                    pack_bf(fmaxf(acc[i][mt][2] + bv.z, 0.f), fmaxf(acc[i][mt][3] + bv.w, 0.f)));
                *(uint2*)(hid + row * 256 + ((chunk ^ (row & 15)) << 3) + (quad & 1) * 4) = q;
            }
        }
    }
    __syncthreads();

    {   // fused GEMM2^T (node): N=64, K=256 -> f32 out
        f32x4 acc[4];
        #pragma unroll
        for (int mt = 0; mt < 4; ++mt) acc[mt] = f32x4{0.f,0.f,0.f,0.f};
        const u16* w2 = frag + 65536;    // [4][8][64][8], ntile = wave
        #pragma unroll
        for (int kblk = 0; kblk < 8; ++kblk) {
            short8 bf[4], af;
            int chunk = kblk * 4 + quad;
            #pragma unroll
            for (int mt = 0; mt < 4; ++mt) {
                int row = mt*16 + lane15;
                bf[mt] = *(const short8*)(hid + row * 256 + ((chunk ^ (row & 15)) << 3));
            }
            af = *(const short8*)(w2 + ((wave*8 + kblk)*64 + l) * 8);
            #pragma unroll
            for (int mt = 0; mt < 4; ++mt)
                acc[mt] = __builtin_amdgcn_mfma_f32_16x16x32_bf16(af, bf[mt], acc[mt], 0, 0, 0);
        }
        int n0 = wave*16 + quad*4;
        float4 bv = *(const float4*)(bias2 + 64 + n0);
        #pragma unroll
        for (int mt = 0; mt < 4; ++mt) {
            int m = mt*16 + lane15;
            if (m < valid) {
                float4 o;
                o.x = acc[mt][0] + bv.x; o.y = acc[mt][1] + bv.y;
                o.z = acc[mt][2] + bv.z; o.w = acc[mt][3] + bv.w;
                *(float4*)(out + (size_t)(r0 + m) * 64 + n0) = o;
            }
        }
    }

    if (!emitAB) return;
    __syncthreads();   // all GEMM2 hid reads done; hid reusable as stg

    // Edge per-node halves: T=0 -> At (+eb1), T=1 -> Ab. xs still holds x tile.
    const u16* w1 = frag;    // [16 ntile][4 kblk][64][8]; kblk 0-1 = top, 2-3 = bot
    for (int T = 0; T < 2; ++T) {
        f32x4 acc[4][4];
        #pragma unroll
        for (int i = 0; i < 4; ++i)
            #pragma unroll
            for (int mt = 0; mt < 4; ++mt) acc[i][mt] = f32x4{0.f,0.f,0.f,0.f};
        #pragma unroll
        for (int kblk = 0; kblk < 2; ++kblk) {
            short8 bf[4], af[4];
            int chunk = kblk * 4 + quad;
            #pragma unroll
            for (int mt = 0; mt < 4; ++mt) {
                int row = mt*16 + lane15;
                bf[mt] = *(const short8*)(xs + row * 64 + ((chunk ^ (row & 7)) << 3));
            }
            #pragma unroll
            for (int i = 0; i < 4; ++i)
                af[i] = *(const short8*)(w1 + (((wave*4 + i)*4 + T*2 + kblk)*64 + l) * 8);
            #pragma unroll
            for (int i = 0; i < 4; ++i)
                #pragma unroll
                for (int mt = 0; mt < 4; ++mt)
                    acc[i][mt] = __builtin_amdgcn_mfma_f32_16x16x32_bf16(af[i], bf[mt], acc[i][mt], 0, 0, 0);
        }
        #pragma unroll
        for (int i = 0; i < 4; ++i) {
            int ntile = wave*4 + i;
            int n0 = ntile*16 + quad*4;
            float4 bv;
            if (T == 0) bv = *(const float4*)(eb1 + n0);
            else        bv = make_float4(0.f, 0.f, 0.f, 0.f);
            int c16 = ntile*2 + (quad >> 1);
            #pragma unroll
            for (int mt = 0; mt < 4; ++mt) {
                int row = mt*16 + lane15;
                uint2 q = make_uint2(
                    pack_h2(acc[i][mt][0] + bv.x, acc[i][mt][1] + bv.y),
                    pack_h2(acc[i][mt][2] + bv.z, acc[i][mt][3] + bv.w));
                *(uint2*)(hid + row * 256 + ((c16 ^ (row & 7)) << 3) + (quad & 1) * 4) = q;
            }
        }
        __syncthreads();
        u16* dst = (T == 0) ? At : Ab;
        #pragma unroll
        for (int it = 0; it < 8; ++it) {
            int i = t + it * 256;          // 0..2047
            int m = i >> 5, c = i & 31;
            if (m < valid)
                ((uint4*)dst)[((size_t)(r0 + m)) * 32 + c] =
                    *(const uint4*)(hid + m * 256 + ((c ^ (m & 7)) << 3));
        }
        __syncthreads();   // hid reuse for T=1
    }
}

// ---------------------------------------------------------------------------
// Edge precompute (FALLBACK path only): per-batch At/Ab from xbf.
// ---------------------------------------------------------------------------
__global__ __launch_bounds__(256) void edge_pre_kernel(
    const u16* __restrict__ xbf, const float* __restrict__ eb1,
    const u16* __restrict__ frag, u16* __restrict__ At, u16* __restrict__ Ab,
    int b)
{
    __shared__ u16 xs[64 * 64];
    __shared__ u16 stg[64 * 256];
    const int t = threadIdx.x;
    const int wave = t >> 6, l = t & 63, lane15 = l & 15, quad = l >> 4;
    const int r0 = blockIdx.x * 64;
    const int valid = min(64, NN - r0);

    #pragma unroll
    for (int it = 0; it < 2; ++it) {
        int i = t + it * 256;
        int m = i >> 3, c = i & 7;
        int row = min(r0 + m, NN - 1);
        uint4 q = ((const uint4*)xbf)[((size_t)(b * NN + row)) * 8 + c];
        *(uint4*)(xs + m * 64 + ((c ^ (m & 7)) << 3)) = q;
    }
    __syncthreads();

    const u16* w1 = frag;
    for (int T = 0; T < 2; ++T) {
        f32x4 acc[4][4];
        #pragma unroll
        for (int i = 0; i < 4; ++i)
            #pragma unroll
            for (int mt = 0; mt < 4; ++mt) acc[i][mt] = f32x4{0.f,0.f,0.f,0.f};
        #pragma unroll
        for (int kblk = 0; kblk < 2; ++kblk) {
            short8 bf[4], af[4];
            int chunk = kblk * 4 + quad;
            #pragma unroll
            for (int mt = 0; mt < 4; ++mt) {
                int row = mt*16 + lane15;
                bf[mt] = *(const short8*)(xs + row * 64 + ((chunk ^ (row & 7)) << 3));
            }
            #pragma unroll
            for (int i = 0; i < 4; ++i)
                af[i] = *(const short8*)(w1 + (((wave*4 + i)*4 + T*2 + kblk)*64 + l) * 8);
            #pragma unroll
            for (int i = 0; i < 4; ++i)
                #pragma unroll
                for (int mt = 0; mt < 4; ++mt)
                    acc[i][mt] = __builtin_amdgcn_mfma_f32_16x16x32_bf16(af[i], bf[mt], acc[i][mt], 0, 0, 0);
        }
        #pragma unroll
        for (int i = 0; i < 4; ++i) {
            int ntile = wave*4 + i;
            int n0 = ntile*16 + quad*4;
            float4 bv;
            if (T == 0) bv = *(const float4*)(eb1 + n0);
            else        bv = make_float4(0.f, 0.f, 0.f, 0.f);
            int c16 = ntile*2 + (quad >> 1);
            #pragma unroll
            for (int mt = 0; mt < 4; ++mt) {
                int row = mt*16 + lane15;
                uint2 q = make_uint2(
                    pack_h2(acc[i][mt][0] + bv.x, acc[i][mt][1] + bv.y),
                    pack_h2(acc[i][mt][2] + bv.z, acc[i][mt][3] + bv.w));
                *(uint2*)(stg + row * 256 + ((c16 ^ (row & 7)) << 3) + (quad & 1) * 4) = q;
            }
        }
        __syncthreads();
        u16* dst = (T == 0) ? At : Ab;
        #pragma unroll
        for (int it = 0; it < 8; ++it) {
            int i = t + it * 256;
            int m = i >> 5, c = i & 31;
            if (m < valid)
                ((uint4*)dst)[((size_t)(r0 + m)) * 32 + c] =
                    *(const uint4*)(stg + m * 256 + ((c ^ (m & 7)) << 3));
        }
        __syncthreads();
    }
}

// ---------------------------------------------------------------------------
// Edge combine + GEMM2 over u-SORTED edges: hid = relu(At[u] + Ab[v]) (f16),
// fused W2' GEMM (f16 MFMA) -> one bf16 row per edge at its u-sorted slot.
// rowStride4/dstOff4 select dense (8,0) or batch-interleaved (16, b*8) layout.
// ---------------------------------------------------------------------------
__global__ __launch_bounds__(256) void edge_emb2_kernel(
    const u16* __restrict__ At, const u16* __restrict__ Ab,
    const int2* __restrict__ uv, const float* __restrict__ bias2,
    const u16* __restrict__ frag, u16* __restrict__ perm,
    int rowStride4, int dstOff4)
{
    __shared__ u16 hid[64 * 128];   // 16 KB f16, 16 chunks/row, mask 15
    __shared__ int us[64], vs[64];
    const int t = threadIdx.x;
    const int wave = t >> 6, l = t & 63, lane15 = l & 15, quad = l >> 4;
    const int e0 = blockIdx.x * 64;
    const int valid = min(64, NE - e0);

    if (t < 64) {
        int2 p = uv[min(e0 + t, NE - 1)];
        us[t] = p.x;
        vs[t] = p.y;
    }
    __syncthreads();

    f32x4 acc[4];
    #pragma unroll
    for (int mt = 0; mt < 4; ++mt) acc[mt] = f32x4{0.f,0.f,0.f,0.f};
    const u16* w2 = frag + 49152;    // [4 ntile][8 kblk][64][8] f16, ntile = wave

    #pragma unroll
    for (int half = 0; half < 2; ++half) {
        // combine: 64 edges x 16 chunks of 16B (K-half); 4 chunks/thread
        #pragma unroll
        for (int it = 0; it < 4; ++it) {
            int i = t + it * 256;           // 0..1023
            int m = i >> 4, c = i & 15;
            int cg = half * 16 + c;
            int u = us[m], v = vs[m];
            uint4 a = ((const uint4*)At)[(size_t)((u32)u) * 32 + cg];
            uint4 bq = ((const uint4*)Ab)[(size_t)((u32)v) * 32 + cg];
            uint4 r;
            r.x = pk_relu_h2(pk_add_h2(a.x, bq.x));
            r.y = pk_relu_h2(pk_add_h2(a.y, bq.y));
            r.z = pk_relu_h2(pk_add_h2(a.z, bq.z));
            r.w = pk_relu_h2(pk_add_h2(a.w, bq.w));
            *(uint4*)(hid + m * 128 + ((c ^ (m & 15)) << 3)) = r;
        }
        __syncthreads();

        // GEMM2^T quarter: N=64, K=128 (this half), f16 MFMA
        #pragma unroll
        for (int kb = 0; kb < 4; ++kb) {
            short8 bf[4], af;
            int chunk = kb * 4 + quad;      // local chunk 0..15
            #pragma unroll
            for (int mt = 0; mt < 4; ++mt) {
                int row = mt*16 + lane15;
                bf[mt] = *(const short8*)(hid + row * 128 + ((chunk ^ (row & 15)) << 3));
            }
            af = *(const short8*)(w2 + ((wave*8 + half*4 + kb)*64 + l) * 8);
            #pragma unroll
            for (int mt = 0; mt < 4; ++mt)
                acc[mt] = __builtin_amdgcn_mfma_f32_16x16x32_f16(as_h8(af), as_h8(bf[mt]), acc[mt], 0, 0, 0);
        }
        __syncthreads();   // hid reusable (next half / epilogue)
    }

    {   // epilogue: bf16 rows into hid[0..8KB), 8 chunks/row, mask 7
        int n0 = wave*16 + quad*4;
        int chunk = wave*2 + (quad >> 1);
        float4 bv = *(const float4*)(bias2 + n0);
        #pragma unroll
        for (int mt = 0; mt < 4; ++mt) {
            int m = mt*16 + lane15;
            uint2 q = make_uint2(
                pack_bf(acc[mt][0] + bv.x, acc[mt][1] + bv.y),
                pack_bf(acc[mt][2] + bv.z, acc[mt][3] + bv.w));
            *(uint2*)(hid + m * 64 + ((chunk ^ (m & 7)) << 3) + (quad & 1) * 4) = q;
        }
    }
    __syncthreads();

    // store: one 128B bf16 row per edge at its u-sorted slot
    #pragma unroll
    for (int it = 0; it < 2; ++it) {
        int i = t + it * 256;          // 0..511
        int m = i >> 3, c8 = i & 7;
        if (m < valid)
            ((uint4*)perm)[(size_t)(e0 + m) * rowStride4 + dstOff4 + c8] =
                *(const uint4*)(hid + m * 64 + ((c8 ^ (m & 7)) << 3));
    }
}

// ---------------------------------------------------------------------------
// FALLBACK gather (per batch, dense 128B rows): as round 4.
// ---------------------------------------------------------------------------
__global__ __launch_bounds__(256) void gather3_kernel(
    const u32* __restrict__ perm32, const int* __restrict__ uoff,
    const int* __restrict__ voff, const int* __restrict__ vmap,
    float* __restrict__ out, int b)
{
    const int t = threadIdx.x, wave = t >> 6, l = t & 63;
    const int n = blockIdx.x * 4 + wave;
    const int ub = uoff[n], ucnt = uoff[n + 1] - ub;
    const int vb = voff[n], vcnt = voff[n + 1] - vb;
    if ((ucnt | vcnt) == 0) return;
    const int slot = l >> 4, c8h = l & 15;
    float a0 = 0.f, a1 = 0.f, a2 = 0.f, a3 = 0.f;

    for (int j0 = 0; j0 < ucnt; j0 += 8) {
        int jA = j0 + slot, jB = j0 + 4 + slot;
        const u32* rpA = perm32 + (size_t)(ub + min(jA, ucnt - 1)) * 32 + 2 * c8h;
        const u32* rpB = perm32 + (size_t)(ub + min(jB, ucnt - 1)) * 32 + 2 * c8h;
        u32 wA0 = rpA[0], wA1 = rpA[1];
        u32 wB0 = rpB[0], wB1 = rpB[1];
        union { u32 u; float f; } x0, x1, x2, x3;
        if (jA < ucnt) {
            x0.u = wA0 << 16; x1.u = wA0 & 0xffff0000u;
            x2.u = wA1 << 16; x3.u = wA1 & 0xffff0000u;
            a0 += x0.f; a1 += x1.f; a2 += x2.f; a3 += x3.f;
        }
        if (jB < ucnt) {
            x0.u = wB0 << 16; x1.u = wB0 & 0xffff0000u;
            x2.u = wB1 << 16; x3.u = wB1 & 0xffff0000u;
            a0 += x0.f; a1 += x1.f; a2 += x2.f; a3 += x3.f;
        }
    }
    for (int j0 = 0; j0 < vcnt; j0 += 8) {
        int jA = j0 + slot, jB = j0 + 4 + slot;
        int pA = vmap[vb + min(jA, vcnt - 1)];
        int pB = vmap[vb + min(jB, vcnt - 1)];
        const u32* rpA = perm32 + (size_t)pA * 32 + 2 * c8h;
        const u32* rpB = perm32 + (size_t)pB * 32 + 2 * c8h;
        u32 wA0 = rpA[0], wA1 = rpA[1];
        u32 wB0 = rpB[0], wB1 = rpB[1];
        union { u32 u; float f; } x0, x1, x2, x3;
        if (jA < vcnt) {
            x0.u = wA0 << 16; x1.u = wA0 & 0xffff0000u;
            x2.u = wA1 << 16; x3.u = wA1 & 0xffff0000u;
            a0 += x0.f; a1 += x1.f; a2 += x2.f; a3 += x3.f;
        }
        if (jB < vcnt) {
            x0.u = wB0 << 16; x1.u = wB0 & 0xffff0000u;
            x2.u = wB1 << 16; x3.u = wB1 & 0xffff0000u;
            a0 += x0.f; a1 += x1.f; a2 += x2.f; a3 += x3.f;
        }
    }

    a0 += __shfl_xor(a0, 16); a1 += __shfl_xor(a1, 16);
    a2 += __shfl_xor(a2, 16); a3 += __shfl_xor(a3, 16);
    a0 += __shfl_xor(a0, 32); a1 += __shfl_xor(a1, 32);
    a2 += __shfl_xor(a2, 32); a3 += __shfl_xor(a3, 32);
    if (l < 16) {
        float4* p = (float4*)(out + (size_t)(b * NN + n) * 64 + 4 * l);
        float4 h = *p;
        h.x += a0; h.y += a1; h.z += a2; h.w += a3;
        *p = h;
    }
}

// ---------------------------------------------------------------------------
// FUSED gather: perm rows are 256B = [batch0 128B][batch1 128B]. One pass
// accumulates both batches for node n (u-run contiguous + v-list indirect).
// ---------------------------------------------------------------------------
#define ACCUM8(q) { union { u32 u; float f; } xx;                         \
    xx.u = (q).x << 16;          a0 += xx.f;                              \
    xx.u = (q).x & 0xffff0000u;  a1 += xx.f;                              \
    xx.u = (q).y << 16;          a2 += xx.f;                              \
    xx.u = (q).y & 0xffff0000u;  a3 += xx.f;                              \
    xx.u = (q).z << 16;          a4 += xx.f;                              \
    xx.u = (q).z & 0xffff0000u;  a5 += xx.f;                              \
    xx.u = (q).w << 16;          a6 += xx.f;                              \
    xx.u = (q).w & 0xffff0000u;  a7 += xx.f; }

__global__ __launch_bounds__(256) void gather4_kernel(
    const u32* __restrict__ perm32, const int* __restrict__ uoff,
    const int* __restrict__ voff, const int* __restrict__ vmap,
    float* __restrict__ out)
{
    const int t = threadIdx.x, wave = t >> 6, l = t & 63;
    const int n = blockIdx.x * 4 + wave;
    const int ub = uoff[n], ucnt = uoff[n + 1] - ub;
    const int vb = voff[n], vcnt = voff[n + 1] - vb;
    if ((ucnt | vcnt) == 0) return;
    const int sg = l >> 4, c16 = l & 15;   // 4 slots/group, 16B col in 256B row
    float a0=0.f,a1=0.f,a2=0.f,a3=0.f,a4=0.f,a5=0.f,a6=0.f,a7=0.f;

    for (int j0 = 0; j0 < ucnt; j0 += 8) {
        int jA = j0 + sg, jB = j0 + 4 + sg;
        uint4 qA = *(const uint4*)(perm32 + (size_t)(ub + min(jA, ucnt - 1)) * 64 + c16 * 4);
        uint4 qB = *(const uint4*)(perm32 + (size_t)(ub + min(jB, ucnt - 1)) * 64 + c16 * 4);
        if (jA < ucnt) ACCUM8(qA);
        if (jB < ucnt) ACCUM8(qB);
    }
    for (int j0 = 0; j0 < vcnt; j0 += 8) {
        int jA = j0 + sg, jB = j0 + 4 + sg;
        int pA = vmap[vb + min(jA, vcnt - 1)];
        int pB = vmap[vb + min(jB, vcnt - 1)];
        uint4 qA = *(const uint4*)(perm32 + (size_t)pA * 64 + c16 * 4);
        uint4 qB = *(const uint4*)(perm32 + (size_t)pB * 64 + c16 * 4);
        if (jA < vcnt) ACCUM8(qA);
        if (jB < vcnt) ACCUM8(qB);
    }

    a0 += __shfl_xor(a0, 16); a1 += __shfl_xor(a1, 16);
    a2 += __shfl_xor(a2, 16); a3 += __shfl_xor(a3, 16);
    a4 += __shfl_xor(a4, 16); a5 += __shfl_xor(a5, 16);
    a6 += __shfl_xor(a6, 16); a7 += __shfl_xor(a7, 16);
    a0 += __shfl_xor(a0, 32); a1 += __shfl_xor(a1, 32);
    a2 += __shfl_xor(a2, 32); a3 += __shfl_xor(a3, 32);
    a4 += __shfl_xor(a4, 32); a5 += __shfl_xor(a5, 32);
    a6 += __shfl_xor(a6, 32); a7 += __shfl_xor(a7, 32);

    if (l < 16) {   // lane = c16: 0..7 -> batch0 cols, 8..15 -> batch1 cols
        float* p = out + ((size_t)((l >> 3) * NN + n)) * 64 + (l & 7) * 8;
        float4 h0 = *(float4*)p, h1 = *(float4*)(p + 4);
        h0.x += a0; h0.y += a1; h0.z += a2; h0.w += a3;
        h1.x += a4; h1.y += a5; h1.z += a6; h1.w += a7;
        *(float4*)p = h0; *(float4*)(p + 4) = h1;
    }
}

// ---------------------------------------------------------------------------
extern "C" void kernel_launch(void* const* d_in, const int* in_sizes, int n_in,
                              void* d_out, int out_size, void* d_ws, size_t ws_size,
                              hipStream_t stream) {
    const float* x     = (const float*)d_in[0];
    const int*   edges = (const int*)d_in[1];
    const float* ew1   = (const float*)d_in[2];
    const float* eb1   = (const float*)d_in[3];
    const float* ew2   = (const float*)d_in[4];
    const float* eb2   = (const float*)d_in[5];
    const float* nw1   = (const float*)d_in[6];
    const float* nb1   = (const float*)d_in[7];
    const float* nw2   = (const float*)d_in[8];
    const float* nb2   = (const float*)d_in[9];
    const float* dw    = (const float*)d_in[10];
    const float* db    = (const float*)d_in[11];
    float* out = (float*)d_out;    // [BN][64]

    // Workspace layout (512B aligned)
    char* w = (char*)d_ws;
    size_t o = 0;
    auto take = [&](size_t bytes) { char* p = w + o; o = (o + bytes + 511) & ~(size_t)511; return p; };
    u16*   frag   = (u16*)  take(81920 * 2);                   // 160 KB
    float* bias2  = (float*)take(128 * 4);
    int*   curU   = (int*)  take((size_t)NN * 4);
    int*   curV   = (int*)  take((size_t)NN * 4);
    int*   uoff   = (int*)  take((size_t)(NN + 1) * 4);
    int*   voff   = (int*)  take((size_t)(NN + 1) * 4);
    int*   bsum2  = (int*)  take((size_t)2 * (NSB + 1) * 4);
    int*   boff2  = (int*)  take((size_t)2 * (NSB + 1) * 4);
    int*   upos   = (int*)  take((size_t)NE * 4);              // 2 MB
    int*   vmap   = (int*)  take((size_t)NE * 4);              // 2 MB
    int2*  uv     = (int2*) take((size_t)NE * 8);              // 4 MB
    size_t oCommon = o;

    // Fused layout: At/Ab for BOTH batches + interleaved perm (256B rows)
    u16* At   = (u16*)take((size_t)BN * 256 * 2);              // 51.2 MB
    u16* Ab   = (u16*)take((size_t)BN * 256 * 2);              // 51.2 MB
    u16* perm = (u16*)take((size_t)NE * 128 * 2);              // 128 MB
    bool fused = (o <= ws_size);

    u16 *xbf = nullptr;
    if (!fused) {   // fallback layout: per-batch tables + dense perm
        o = oCommon;
        xbf  = (u16*)take((size_t)BN * 64 * 2);                // 12.8 MB
        At   = (u16*)take((size_t)NN * 256 * 2);               // 25.6 MB
        Ab   = (u16*)take((size_t)NN * 256 * 2);               // 25.6 MB
        perm = (u16*)take((size_t)NE * 64 * 2);                // 64 MB
    }

    // Dual CSR build (edges batch-invariant)
    csr_zero2<<<NSB, 256, 0, stream>>>(curU, curV);
    csr_hist2<<<(NE + 255) / 256, 256, 0, stream>>>(edges, curU, curV);
    scan_pass1d<<<dim3(NSB, 2), 256, 0, stream>>>(curU, curV, bsum2);
    scan_pass2d<<<dim3(1, 2), 256, 0, stream>>>(bsum2, boff2);
    scan_pass3d<<<dim3(NSB, 2), 256, 0, stream>>>(curU, curV, boff2, uoff, voff);
    csr_fillU<<<(NE + 255) / 256, 256, 0, stream>>>(edges, curU, uv, upos);
    csr_fillV<<<(NE + 255) / 256, 256, 0, stream>>>(edges, curV, upos, vmap);

    // Weight prep
    weight_prep<<<321, 256, 0, stream>>>(ew1, nw1, ew2, nw2, dw, db, eb2, nb2, frag, bias2);

    // Node term -> out base (+ At/Ab for both batches when fused)
    node_mlp_kernel<<<(BN + 63) / 64, 256, 0, stream>>>(
        x, nb1, eb1, bias2, frag, xbf, At, Ab, out, fused ? 1 : 0);

    if (fused) {
        for (int b = 0; b < BB; ++b) {
            edge_emb2_kernel<<<(NE + 63) / 64, 256, 0, stream>>>(
                At + (size_t)b * NN * 256, Ab + (size_t)b * NN * 256,
                uv, bias2, frag, perm, 16, b * 8);
        }
        gather4_kernel<<<NN / 4, 256, 0, stream>>>((const u32*)perm, uoff, voff, vmap, out);
    } else {
        for (int b = 0; b < BB; ++b) {
            edge_pre_kernel<<<(NN + 63) / 64, 256, 0, stream>>>(xbf, eb1, frag, At, Ab, b);
            edge_emb2_kernel<<<(NE + 63) / 64, 256, 0, stream>>>(
                At, Ab, uv, bias2, frag, perm, 8, 0);
            gather3_kernel<<<NN / 4, 256, 0, stream>>>((const u32*)perm, uoff, voff, vmap, out, b);
        }
    }
}

// Round 7
// 407.320 us; speedup vs baseline: 1.2486x; 1.0290x over previous
//
#include <hip/hip_runtime.h>
#include <hip/hip_bf16.h>

// Problem constants
#define BB   2
#define NN   50000
#define BN   100000     // B*N
#define NE   500000
#define NSB  196        // scan blocks = ceil(NN/256)
#define NODE_NB 1563    // ceil(BN/64)

using u16 = unsigned short;
using u32 = unsigned int;
typedef __attribute__((ext_vector_type(8))) short short8;      // 8 x bf16/f16 bits
typedef __attribute__((ext_vector_type(8))) _Float16 half8;    // 8 x f16 (4 VGPRs)
typedef __attribute__((ext_vector_type(4))) float f32x4;       // MFMA accumulator

__device__ __forceinline__ u16 f2bf(float f) {   // RNE f32 -> bf16 (finite inputs)
    union { float f; u32 u; } w; w.f = f;
    return (u16)((w.u + 0x7fffu + ((w.u >> 16) & 1u)) >> 16);
}
__device__ __forceinline__ u16 f2h(float f) {    // RNE f32 -> f16
    _Float16 h = (_Float16)f; u16 u; __builtin_memcpy(&u, &h, 2); return u;
}

#if defined(__has_builtin)
#if __has_builtin(__builtin_amdgcn_cvt_pk_bf16_f32)
#define HAVE_CVTPK 1
#endif
#if __has_builtin(__builtin_amdgcn_cvt_pkrtz)
#define HAVE_PKRTZ 1
#endif
#endif

__device__ __forceinline__ u32 pack_bf(float lo, float hi) {
#ifdef HAVE_CVTPK
    auto r = __builtin_amdgcn_cvt_pk_bf16_f32(lo, hi);
    u32 out; __builtin_memcpy(&out, &r, sizeof(out));
    return out;
#else
    return ((u32)f2bf(hi) << 16) | (u32)f2bf(lo);
#endif
}

__device__ __forceinline__ u32 pack_h2(float lo, float hi) {
#ifdef HAVE_PKRTZ
    auto r = __builtin_amdgcn_cvt_pkrtz(lo, hi);
    u32 out; __builtin_memcpy(&out, &r, sizeof(out));
    return out;
#else
    return ((u32)f2h(hi) << 16) | (u32)f2h(lo);
#endif
}

__device__ __forceinline__ u32 pk_add_h2(u32 a, u32 b) {
    u32 d; asm("v_pk_add_f16 %0, %1, %2" : "=v"(d) : "v"(a), "v"(b)); return d;
}
__device__ __forceinline__ u32 pk_relu_h2(u32 a) {
    u32 d, z = 0u;
    asm("v_pk_max_f16 %0, %1, %2" : "=v"(d) : "v"(a), "v"(z)); return d;
}
__device__ __forceinline__ half8 as_h8(short8 s) {
    half8 h; __builtin_memcpy(&h, &s, 16); return h;
}

// ---------------------------------------------------------------------------
// Weight prep (blocks 0..320) fused with CSR histogram (blocks 321..).
// frag regions (u16): w1e @0 ([16][4][64][8] bf16), w1n @32768 ([16][2][64][8]),
//                     w2e' @49152 ([4][8][64][8] f16), w2n' @65536 (bf16).
// ---------------------------------------------------------------------------
__global__ __launch_bounds__(256) void weight_prep_hist(
    const float* __restrict__ ew1, const float* __restrict__ nw1,
    const float* __restrict__ ew2, const float* __restrict__ nw2,
    const float* __restrict__ dw,  const float* __restrict__ db,
    const float* __restrict__ eb2, const float* __restrict__ nb2,
    const int* __restrict__ edges, int* __restrict__ curU, int* __restrict__ curV,
    u16* __restrict__ frag, float* __restrict__ bias2)
{
    int blk = blockIdx.x, t = threadIdx.x;
    if (blk >= 321) {                       // CSR histogram (independent work)
        int e = (blk - 321) * 256 + t;
        if (e < NE) {
            atomicAdd(&curU[edges[2*e]], 1);
            atomicAdd(&curV[edges[2*e+1]], 1);
        }
        return;
    }
    if (blk < 192) {
        int idx = blk * 256 + t;                 // 0..49151
        const float* src; int KB, local;
        if (idx < 32768) { local = idx;         src = ew1; KB = 4; }
        else             { local = idx - 32768; src = nw1; KB = 2; }
        int j = local & 7, l = (local >> 3) & 63, rest = local >> 9;
        int kblk = rest % KB, ntile = rest / KB;
        int n = ntile * 16 + (l & 15);
        int k = kblk * 32 + ((l >> 4) << 3) + j;
        frag[idx] = f2bf(src[k * 256 + n]);
    } else if (blk < 320) {
        int idx = (blk - 192) * 256 + t;         // 0..32767
        bool is_e = (idx < 16384);
        const float* src = is_e ? ew2 : nw2;
        int local = idx & 16383;
        int j = local & 7, l = (local >> 3) & 63, rest = local >> 9;
        int kblk = rest & 7, ntile = rest >> 3;
        int n = ntile * 16 + (l & 15);
        int k = kblk * 32 + ((l >> 4) << 3) + j;
        float s = 0.f;
        for (int jj = 0; jj < 128; ++jj) s = fmaf(src[k * 128 + jj], dw[jj * 64 + n], s);
        frag[49152 + idx] = is_e ? f2h(s) : f2bf(s);
    } else if (t < 128) {
        int d = t & 63;
        const float* bsrc = (t >= 64) ? nb2 : eb2;
        float s = 0.f;
        #pragma unroll 4
        for (int j = 0; j < 128; ++j) s = fmaf(bsrc[j], dw[j * 64 + d], s);
        if (t >= 64) bias2[64 + d] = s + db[d];
        else         bias2[d] = s;
    }
}

// ---------------------------------------------------------------------------
// scan passes 2/3 (y = 0 -> U, y = 1 -> V)
// ---------------------------------------------------------------------------
__global__ __launch_bounds__(256) void scan_pass2d(const int* __restrict__ bsum2,
                                                   int* __restrict__ boff2) {
    __shared__ int s[256];
    const int t = threadIdx.x;
    const int base = blockIdx.y * (NSB + 1);
    s[t] = (t < NSB) ? bsum2[base + t] : 0;
    __syncthreads();
    for (int d = 1; d < 256; d <<= 1) {
        int v = (t >= d) ? s[t - d] : 0;
        __syncthreads();
        s[t] += v;
        __syncthreads();
    }
    if (t <= NSB) boff2[base + t] = (t == 0) ? 0 : s[t - 1];
}

__global__ __launch_bounds__(256) void scan_pass3d(int* __restrict__ curU,
                                                   int* __restrict__ curV,
                                                   const int* __restrict__ boff2,
                                                   int* __restrict__ uoff,
                                                   int* __restrict__ voff) {
    __shared__ int s[256];
    const int t = threadIdx.x;
    int* cursor = blockIdx.y ? curV : curU;
    int* off    = blockIdx.y ? voff : uoff;
    const int base = blockIdx.y * (NSB + 1);
    int i = blockIdx.x * 256 + t;
    int v = (i < NN) ? cursor[i] : 0;
    s[t] = v;
    __syncthreads();
    for (int d = 1; d < 256; d <<= 1) {
        int p = (t >= d) ? s[t - d] : 0;
        __syncthreads();
        s[t] += p;
        __syncthreads();
    }
    int excl = boff2[base + blockIdx.x] + s[t] - v;
    if (i < NN) { off[i] = excl; cursor[i] = excl; }
    if (i == NN - 1) off[NN] = excl + v;
}

// ---------------------------------------------------------------------------
// Fused CSR fill: u-slot (uv row + slot id) and v-slot (vmap -> u-slot) in one
// pass; the old upos array is unnecessary (same-thread data).
// ---------------------------------------------------------------------------
__global__ __launch_bounds__(256) void csr_fill2(const int* __restrict__ edges,
                                                 int* __restrict__ curU,
                                                 int* __restrict__ curV,
                                                 int2* __restrict__ uv,
                                                 int* __restrict__ vmap) {
    int e = blockIdx.x * 256 + threadIdx.x;
    if (e < NE) {
        int u = edges[2*e], v = edges[2*e+1];
        int s0 = atomicAdd(&curU[u], 1);
        uv[s0] = make_int2(u, v);
        int s1 = atomicAdd(&curV[v], 1);
        vmap[s1] = s0;
    }
}

// ---------------------------------------------------------------------------
// Node MLP (dw-fused) + edge-MLP per-node halves At/Ab for ALL BN rows.
// 24 KB LDS (xs 8K + hid 16K): hidden dim processed in two 128-wide halves so
// 6 blocks/CU fit (was 40 KB -> 4). Also absorbs scan_pass1 (blocks >= NODE_NB).
// ---------------------------------------------------------------------------
__global__ __launch_bounds__(256) void node_mlp_kernel(
    const float* __restrict__ x, const float* __restrict__ nb1,
    const float* __restrict__ eb1, const float* __restrict__ bias2,
    const u16* __restrict__ frag,
    u16* __restrict__ At, u16* __restrict__ Ab, float* __restrict__ out,
    const int* __restrict__ curU, const int* __restrict__ curV,
    int* __restrict__ bsum2)
{
    __shared__ u16 xs[64 * 64];     // 8 KB, 8 chunks/row, swizzle mask 7
    __shared__ u16 hid[64 * 128];   // 16 KB, 16 chunks/row, swizzle mask 15
    const int t = threadIdx.x;

    if (blockIdx.x >= NODE_NB) {    // fused scan_pass1 for U and V histograms
        int sb = blockIdx.x - NODE_NB;       // 0..2*NSB-1
        int y = sb / NSB, xi = sb - y * NSB;
        const int* cursor = y ? curV : curU;
        int* s = (int*)xs;
        int i = xi * 256 + t;
        s[t] = (i < NN) ? cursor[i] : 0;
        __syncthreads();
        for (int d = 128; d > 0; d >>= 1) {
            if (t < d) s[t] += s[t + d];
            __syncthreads();
        }
        if (t == 0) bsum2[y * (NSB + 1) + xi] = s[0];
        return;
    }

    const int wave = t >> 6, l = t & 63, lane15 = l & 15, quad = l >> 4;
    const int r0 = blockIdx.x * 64;
    const int valid = min(64, BN - r0);

    // stage + convert x -> xs (bf16)
    #pragma unroll
    for (int it = 0; it < 4; ++it) {
        int i = t + it * 256;          // 0..1023
        int m = i >> 4, c4 = i & 15;   // row, float4-col (8B half-chunk)
        int row = min(r0 + m, BN - 1);
        float4 g = ((const float4*)x)[(size_t)row * 16 + c4];
        uint2 q = make_uint2(pack_bf(g.x, g.y), pack_bf(g.z, g.w));
        int chunk = c4 >> 1;
        *(uint2*)(xs + m * 64 + ((chunk ^ (m & 7)) << 3) + (c4 & 1) * 4) = q;
    }
    __syncthreads();

    // Node MLP: GEMM1 in two hidden halves, GEMM2 accumulates across halves.
    f32x4 acc2[4];
    #pragma unroll
    for (int mt = 0; mt < 4; ++mt) acc2[mt] = f32x4{0.f,0.f,0.f,0.f};
    const u16* w1n = frag + 32768;   // [16 ntile][2 kblk][64][8]
    const u16* w2n = frag + 65536;   // [4 ntile][8 kblk][64][8]
    #pragma unroll
    for (int H = 0; H < 2; ++H) {
        f32x4 acc1[2][4];
        #pragma unroll
        for (int i = 0; i < 2; ++i)
            #pragma unroll
            for (int mt = 0; mt < 4; ++mt) acc1[i][mt] = f32x4{0.f,0.f,0.f,0.f};
        #pragma unroll
        for (int kblk = 0; kblk < 2; ++kblk) {
            short8 bf[4], af[2];
            int chunk = kblk * 4 + quad;
            #pragma unroll
            for (int mt = 0; mt < 4; ++mt) {
                int row = mt*16 + lane15;
                bf[mt] = *(const short8*)(xs + row * 64 + ((chunk ^ (row & 7)) << 3));
            }
            #pragma unroll
            for (int i = 0; i < 2; ++i)
                af[i] = *(const short8*)(w1n + (((H*8 + wave*2 + i)*2 + kblk)*64 + l) * 8);
            #pragma unroll
            for (int i = 0; i < 2; ++i)
                #pragma unroll
                for (int mt = 0; mt < 4; ++mt)
                    acc1[i][mt] = __builtin_amdgcn_mfma_f32_16x16x32_bf16(af[i], bf[mt], acc1[i][mt], 0, 0, 0);
        }
        // epilogue: relu+bias -> bf16 hid half (cols [H*128, H*128+128))
        #pragma unroll
        for (int i = 0; i < 2; ++i) {
            int ntl = wave*2 + i;                  // local col-tile 0..7
            int n0 = (H*8 + ntl)*16 + quad*4;      // global hidden col
            int c16 = ntl*2 + (quad >> 1);         // local 16B chunk 0..15
            float4 bv = *(const float4*)(nb1 + n0);
            #pragma unroll
            for (int mt = 0; mt < 4; ++mt) {
                int row = mt*16 + lane15;
                uint2 q = make_uint2(
                    pack_bf(fmaxf(acc1[i][mt][0] + bv.x, 0.f), fmaxf(acc1[i][mt][1] + bv.y, 0.f)),
                    pack_bf(fmaxf(acc1[i][mt][2] + bv.z, 0.f), fmaxf(acc1[i][mt][3] + bv.w, 0.f)));
                *(uint2*)(hid + row * 128 + ((c16 ^ (row & 15)) << 3) + (quad & 1) * 4) = q;
            }
        }
        __syncthreads();
        // GEMM2 partial over this K-half
        #pragma unroll
        for (int kb = 0; kb < 4; ++kb) {
            short8 bf[4], af;
            int chunk = kb * 4 + quad;
            #pragma unroll
            for (int mt = 0; mt < 4; ++mt) {
                int row = mt*16 + lane15;
                bf[mt] = *(const short8*)(hid + row * 128 + ((chunk ^ (row & 15)) << 3));
            }
            af = *(const short8*)(w2n + ((wave*8 + H*4 + kb)*64 + l) * 8);
            #pragma unroll
            for (int mt = 0; mt < 4; ++mt)
                acc2[mt] = __builtin_amdgcn_mfma_f32_16x16x32_bf16(af, bf[mt], acc2[mt], 0, 0, 0);
        }
        __syncthreads();   // hid reusable (next half / edge phase)
    }
    {   // node output store (f32)
        int n0 = wave*16 + quad*4;
        float4 bv = *(const float4*)(bias2 + 64 + n0);
        #pragma unroll
        for (int mt = 0; mt < 4; ++mt) {
            int m = mt*16 + lane15;
            if (m < valid) {
                float4 o;
                o.x = acc2[mt][0] + bv.x; o.y = acc2[mt][1] + bv.y;
                o.z = acc2[mt][2] + bv.z; o.w = acc2[mt][3] + bv.w;
                *(float4*)(out + (size_t)(r0 + m) * 64 + n0) = o;
            }
        }
    }

    // Edge per-node halves: T=0 -> At (+eb1), T=1 -> Ab; each in 2 hidden halves.
    const u16* w1e = frag;   // [16 ntile][4 kblk][64][8]; kblk 0-1 = top, 2-3 = bot
    #pragma unroll
    for (int T = 0; T < 2; ++T) {
        u16* dst = T ? Ab : At;
        #pragma unroll
        for (int H = 0; H < 2; ++H) {
            f32x4 acc[2][4];
            #pragma unroll
            for (int i = 0; i < 2; ++i)
                #pragma unroll
                for (int mt = 0; mt < 4; ++mt) acc[i][mt] = f32x4{0.f,0.f,0.f,0.f};
            #pragma unroll
            for (int kblk = 0; kblk < 2; ++kblk) {
                short8 bf[4], af[2];
                int chunk = kblk * 4 + quad;
                #pragma unroll
                for (int mt = 0; mt < 4; ++mt) {
                    int row = mt*16 + lane15;
                    bf[mt] = *(const short8*)(xs + row * 64 + ((chunk ^ (row & 7)) << 3));
                }
                #pragma unroll
                for (int i = 0; i < 2; ++i)
                    af[i] = *(const short8*)(w1e + (((H*8 + wave*2 + i)*4 + T*2 + kblk)*64 + l) * 8);
                #pragma unroll
                for (int i = 0; i < 2; ++i)
                    #pragma unroll
                    for (int mt = 0; mt < 4; ++mt)
                        acc[i][mt] = __builtin_amdgcn_mfma_f32_16x16x32_bf16(af[i], bf[mt], acc[i][mt], 0, 0, 0);
            }
            // epilogue -> f16 hid half
            #pragma unroll
            for (int i = 0; i < 2; ++i) {
                int ntl = wave*2 + i;
                int n0 = (H*8 + ntl)*16 + quad*4;
                int c16 = ntl*2 + (quad >> 1);
                float4 bv;
                if (T == 0) bv = *(const float4*)(eb1 + n0);
                else        bv = make_float4(0.f, 0.f, 0.f, 0.f);
                #pragma unroll
                for (int mt = 0; mt < 4; ++mt) {
                    int row = mt*16 + lane15;
                    uint2 q = make_uint2(
                        pack_h2(acc[i][mt][0] + bv.x, acc[i][mt][1] + bv.y),
                        pack_h2(acc[i][mt][2] + bv.z, acc[i][mt][3] + bv.w));
                    *(uint2*)(hid + row * 128 + ((c16 ^ (row & 15)) << 3) + (quad & 1) * 4) = q;
                }
            }
            __syncthreads();
            // store half-rows (256B contiguous per row)
            #pragma unroll
            for (int it = 0; it < 4; ++it) {
                int i = t + it * 256;          // 0..1023
                int m = i >> 4, c = i & 15;
                if (m < valid)
                    ((uint4*)dst)[((size_t)(r0 + m)) * 32 + H*16 + c] =
                        *(const uint4*)(hid + m * 128 + ((c ^ (m & 15)) << 3));
            }
            __syncthreads();   // hid reuse next (T,H)
        }
    }
}

// ---------------------------------------------------------------------------
// Edge combine + GEMM2 over u-SORTED edges, BOTH batches per block:
// hid = relu(At_b[u] + Ab_b[v]) (f16), W2' GEMM (f16 MFMA); one 256B
// interleaved perm row per edge ([batch0 128B][batch1 128B]).
// ---------------------------------------------------------------------------
__global__ __launch_bounds__(256) void edge_emb3_kernel(
    const u16* __restrict__ At, const u16* __restrict__ Ab,
    const int2* __restrict__ uv, const float* __restrict__ bias2,
    const u16* __restrict__ frag, u16* __restrict__ perm)
{
    __shared__ u16 hid[64 * 128];   // 16 KB f16, 16 chunks/row, mask 15
    __shared__ int us[64], vs[64];
    const int t = threadIdx.x;
    const int wave = t >> 6, l = t & 63, lane15 = l & 15, quad = l >> 4;
    const int e0 = blockIdx.x * 64;
    const int valid = min(64, NE - e0);

    if (t < 64) {
        int2 p = uv[min(e0 + t, NE - 1)];
        us[t] = p.x;
        vs[t] = p.y;
    }
    __syncthreads();

    const u16* w2 = frag + 49152;    // [4 ntile][8 kblk][64][8] f16, ntile = wave
    f32x4 accB[2][4];
    #pragma unroll
    for (int b = 0; b < 2; ++b)
        #pragma unroll
        for (int mt = 0; mt < 4; ++mt) accB[b][mt] = f32x4{0.f,0.f,0.f,0.f};

    #pragma unroll
    for (int b = 0; b < 2; ++b) {
        const u16* Atb = At + (size_t)b * NN * 256;
        const u16* Abb = Ab + (size_t)b * NN * 256;
        #pragma unroll
        for (int half = 0; half < 2; ++half) {
            // combine: 64 edges x 16 chunks of 16B (K-half); 4 chunks/thread
            #pragma unroll
            for (int it = 0; it < 4; ++it) {
                int i = t + it * 256;           // 0..1023
                int m = i >> 4, c = i & 15;
                int cg = half * 16 + c;
                int u = us[m], v = vs[m];
                uint4 a = ((const uint4*)Atb)[(size_t)((u32)u) * 32 + cg];
                uint4 bq = ((const uint4*)Abb)[(size_t)((u32)v) * 32 + cg];
                uint4 r;
                r.x = pk_relu_h2(pk_add_h2(a.x, bq.x));
                r.y = pk_relu_h2(pk_add_h2(a.y, bq.y));
                r.z = pk_relu_h2(pk_add_h2(a.z, bq.z));
                r.w = pk_relu_h2(pk_add_h2(a.w, bq.w));
                *(uint4*)(hid + m * 128 + ((c ^ (m & 15)) << 3)) = r;
            }
            __syncthreads();
            // GEMM2^T quarter: N=64, K=128 (this half), f16 MFMA
            #pragma unroll
            for (int kb = 0; kb < 4; ++kb) {
                short8 bf[4], af;
                int chunk = kb * 4 + quad;
                #pragma unroll
                for (int mt = 0; mt < 4; ++mt) {
                    int row = mt*16 + lane15;
                    bf[mt] = *(const short8*)(hid + row * 128 + ((chunk ^ (row & 15)) << 3));
                }
                af = *(const short8*)(w2 + ((wave*8 + half*4 + kb)*64 + l) * 8);
                #pragma unroll
                for (int mt = 0; mt < 4; ++mt)
                    accB[b][mt] = __builtin_amdgcn_mfma_f32_16x16x32_f16(as_h8(af), as_h8(bf[mt]), accB[b][mt], 0, 0, 0);
            }
            __syncthreads();   // hid reusable
        }
    }

    {   // epilogue: both batches' bf16 rows into hid (256B/edge, mask 15)
        int n0 = wave*16 + quad*4;
        float4 bv = *(const float4*)(bias2 + n0);
        #pragma unroll
        for (int b = 0; b < 2; ++b) {
            int cc = b*8 + wave*2 + (quad >> 1);   // 16B chunk 0..15
            #pragma unroll
            for (int mt = 0; mt < 4; ++mt) {
                int m = mt*16 + lane15;
                uint2 q = make_uint2(
                    pack_bf(accB[b][mt][0] + bv.x, accB[b][mt][1] + bv.y),
                    pack_bf(accB[b][mt][2] + bv.z, accB[b][mt][3] + bv.w));
                *(uint2*)(hid + m * 128 + ((cc ^ (m & 15)) << 3) + (quad & 1) * 4) = q;
            }
        }
    }
    __syncthreads();

    // store: one 256B interleaved row per edge at its u-sorted slot
    #pragma unroll
    for (int it = 0; it < 4; ++it) {
        int i = t + it * 256;          // 0..1023
        int m = i >> 4, c = i & 15;
        if (m < valid)
            ((uint4*)perm)[((size_t)(e0 + m)) * 16 + c] =
                *(const uint4*)(hid + m * 128 + ((c ^ (m & 15)) << 3));
    }
}

// ---------------------------------------------------------------------------
// FUSED gather: perm rows are 256B = [batch0 128B][batch1 128B]. One pass
// accumulates both batches for node n (u-run contiguous + v-list indirect).
// ---------------------------------------------------------------------------
#define ACCUM8(q) { union { u32 u; float f; } xx;                         \
    xx.u = (q).x << 16;          a0 += xx.f;                              \
    xx.u = (q).x & 0xffff0000u;  a1 += xx.f;                              \
    xx.u = (q).y << 16;          a2 += xx.f;                              \
    xx.u = (q).y & 0xffff0000u;  a3 += xx.f;                              \
    xx.u = (q).z << 16;          a4 += xx.f;                              \
    xx.u = (q).z & 0xffff0000u;  a5 += xx.f;                              \
    xx.u = (q).w << 16;          a6 += xx.f;                              \
    xx.u = (q).w & 0xffff0000u;  a7 += xx.f; }

__global__ __launch_bounds__(256) void gather4_kernel(
    const u32* __restrict__ perm32, const int* __restrict__ uoff,
    const int* __restrict__ voff, const int* __restrict__ vmap,
    float* __restrict__ out)
{
    const int t = threadIdx.x, wave = t >> 6, l = t & 63;
    const int n = blockIdx.x * 4 + wave;
    const int ub = uoff[n], ucnt = uoff[n + 1] - ub;
    const int vb = voff[n], vcnt = voff[n + 1] - vb;
    if ((ucnt | vcnt) == 0) return;
    const int sg = l >> 4, c16 = l & 15;   // 4 slots/group, 16B col in 256B row
    float a0=0.f,a1=0.f,a2=0.f,a3=0.f,a4=0.f,a5=0.f,a6=0.f,a7=0.f;

    for (int j0 = 0; j0 < ucnt; j0 += 8) {
        int jA = j0 + sg, jB = j0 + 4 + sg;
        uint4 qA = *(const uint4*)(perm32 + (size_t)(ub + min(jA, ucnt - 1)) * 64 + c16 * 4);
        uint4 qB = *(const uint4*)(perm32 + (size_t)(ub + min(jB, ucnt - 1)) * 64 + c16 * 4);
        if (jA < ucnt) ACCUM8(qA);
        if (jB < ucnt) ACCUM8(qB);
    }
    for (int j0 = 0; j0 < vcnt; j0 += 8) {
        int jA = j0 + sg, jB = j0 + 4 + sg;
        int pA = vmap[vb + min(jA, vcnt - 1)];
        int pB = vmap[vb + min(jB, vcnt - 1)];
        uint4 qA = *(const uint4*)(perm32 + (size_t)pA * 64 + c16 * 4);
        uint4 qB = *(const uint4*)(perm32 + (size_t)pB * 64 + c16 * 4);
        if (jA < vcnt) ACCUM8(qA);
        if (jB < vcnt) ACCUM8(qB);
    }

    a0 += __shfl_xor(a0, 16); a1 += __shfl_xor(a1, 16);
    a2 += __shfl_xor(a2, 16); a3 += __shfl_xor(a3, 16);
    a4 += __shfl_xor(a4, 16); a5 += __shfl_xor(a5, 16);
    a6 += __shfl_xor(a6, 16); a7 += __shfl_xor(a7, 16);
    a0 += __shfl_xor(a0, 32); a1 += __shfl_xor(a1, 32);
    a2 += __shfl_xor(a2, 32); a3 += __shfl_xor(a3, 32);
    a4 += __shfl_xor(a4, 32); a5 += __shfl_xor(a5, 32);
    a6 += __shfl_xor(a6, 32); a7 += __shfl_xor(a7, 32);

    if (l < 16) {   // lane = c16: 0..7 -> batch0 cols, 8..15 -> batch1 cols
        float* p = out + ((size_t)((l >> 3) * NN + n)) * 64 + (l & 7) * 8;
        float4 h0 = *(float4*)p, h1 = *(float4*)(p + 4);
        h0.x += a0; h0.y += a1; h0.z += a2; h0.w += a3;
        h1.x += a4; h1.y += a5; h1.z += a6; h1.w += a7;
        *(float4*)p = h0; *(float4*)(p + 4) = h1;
    }
}

// ---------------------------------------------------------------------------
extern "C" void kernel_launch(void* const* d_in, const int* in_sizes, int n_in,
                              void* d_out, int out_size, void* d_ws, size_t ws_size,
                              hipStream_t stream) {
    const float* x     = (const float*)d_in[0];
    const int*   edges = (const int*)d_in[1];
    const float* ew1   = (const float*)d_in[2];
    const float* eb1   = (const float*)d_in[3];
    const float* ew2   = (const float*)d_in[4];
    const float* eb2   = (const float*)d_in[5];
    const float* nw1   = (const float*)d_in[6];
    const float* nb1   = (const float*)d_in[7];
    const float* nw2   = (const float*)d_in[8];
    const float* nb2   = (const float*)d_in[9];
    const float* dw    = (const float*)d_in[10];
    const float* db    = (const float*)d_in[11];
    float* out = (float*)d_out;    // [BN][64]

    // Workspace layout (512B aligned)
    char* w = (char*)d_ws;
    size_t o = 0;
    auto take = [&](size_t bytes) { char* p = w + o; o = (o + bytes + 511) & ~(size_t)511; return p; };
    u16*   frag   = (u16*)  take(81920 * 2);                   // 160 KB
    float* bias2  = (float*)take(128 * 4);
    int*   curU   = (int*)  take((size_t)NN * 4);
    int*   curV   = (int*)  take((size_t)NN * 4);
    int*   uoff   = (int*)  take((size_t)(NN + 1) * 4);
    int*   voff   = (int*)  take((size_t)(NN + 1) * 4);
    int*   bsum2  = (int*)  take((size_t)2 * (NSB + 1) * 4);
    int*   boff2  = (int*)  take((size_t)2 * (NSB + 1) * 4);
    int*   vmap   = (int*)  take((size_t)NE * 4);              // 2 MB
    int2*  uv     = (int2*) take((size_t)NE * 8);              // 4 MB
    u16*   At     = (u16*)  take((size_t)BN * 256 * 2);        // 51.2 MB (both batches)
    u16*   Ab     = (u16*)  take((size_t)BN * 256 * 2);        // 51.2 MB
    u16*   perm   = (u16*)  take((size_t)NE * 128 * 2);        // 128 MB (interleaved)
    (void)ws_size;

    // zero histograms (DMA memsets, replaces a dispatch)
    hipMemsetAsync(curU, 0, (size_t)NN * 4, stream);
    hipMemsetAsync(curV, 0, (size_t)NN * 4, stream);

    // weight prep || CSR histogram (independent work, one dispatch)
    weight_prep_hist<<<321 + (NE + 255) / 256, 256, 0, stream>>>(
        ew1, nw1, ew2, nw2, dw, db, eb2, nb2, edges, curU, curV, frag, bias2);

    // node+edge per-node tables || scan_pass1 (both axes)
    node_mlp_kernel<<<NODE_NB + 2 * NSB, 256, 0, stream>>>(
        x, nb1, eb1, bias2, frag, At, Ab, out, curU, curV, bsum2);

    scan_pass2d<<<dim3(1, 2), 256, 0, stream>>>(bsum2, boff2);
    scan_pass3d<<<dim3(NSB, 2), 256, 0, stream>>>(curU, curV, boff2, uoff, voff);
    csr_fill2<<<(NE + 255) / 256, 256, 0, stream>>>(edges, curU, curV, uv, vmap);

    // edge MLP both batches -> interleaved perm rows
    edge_emb3_kernel<<<(NE + 63) / 64, 256, 0, stream>>>(At, Ab, uv, bias2, frag, perm);

    // one gather for both batches
    gather4_kernel<<<NN / 4, 256, 0, stream>>>((const u32*)perm, uoff, voff, vmap, out);
}